// Round 1
// baseline (1179.691 us; speedup 1.0000x reference)
//
#include <hip/hip_runtime.h>
#include <stdint.h>

typedef unsigned int u32;
typedef unsigned long long u64;

#define BN 8
#define HW_ 65536
#define N1 196608
#define NOPS_ 65536
#define NROWS_ 24576
#define NB1 96
#define NB2 32

// ---------------- sort: key transform + build packed (key|idx) ----------------
__device__ __forceinline__ u32 fkey(float x) {
  u32 u = __float_as_uint(x);
  return u ^ ((u & 0x80000000u) ? 0xFFFFFFFFu : 0x80000000u);
}

__global__ void bk_kernel(const float* __restrict__ x, u64* __restrict__ kv, int n) {
  int i = blockIdx.x * 256 + threadIdx.x;
  u32 k = fkey(x[i]);
  kv[i] = ((u64)k << 32) | (u32)(i % n);
}

// ---------------- radix pass: histogram ----------------
__global__ __launch_bounds__(256) void rs_hist(const u64* __restrict__ kv, u32* __restrict__ hist,
                                               int n, int nblk, int shift) {
  __shared__ u32 h[256];
  int t = threadIdx.x;
  int b = blockIdx.x / nblk, blk = blockIdx.x % nblk;
  h[t] = 0;
  __syncthreads();
  const u64* kp = kv + (size_t)b * n + (size_t)blk * 2048;
#pragma unroll
  for (int j = 0; j < 8; ++j) {
    u32 d = (u32)(kp[j * 256 + t] >> (32 + shift)) & 255u;
    atomicAdd(&h[d], 1u);
  }
  __syncthreads();
  hist[((size_t)b * 256 + t) * nblk + blk] = h[t];
}

// ---------------- radix pass: per-batch exclusive scan (digit-major) ----------------
__global__ __launch_bounds__(256) void rs_scan(u32* __restrict__ hist, int nblk) {
  __shared__ u32 sums[256];
  int b = blockIdx.x, t = threadIdx.x;
  u32* p = hist + (size_t)b * 256 * nblk;
  u32 s = 0;
  for (int j = 0; j < nblk; ++j) s += p[t * nblk + j];
  sums[t] = s;
  __syncthreads();
  for (int off = 1; off < 256; off <<= 1) {
    u32 v = (t >= off) ? sums[t - off] : 0u;
    __syncthreads();
    sums[t] += v;
    __syncthreads();
  }
  u32 run = (t == 0) ? 0u : sums[t - 1];
  for (int j = 0; j < nblk; ++j) { u32 c = p[t * nblk + j]; p[t * nblk + j] = run; run += c; }
}

// ---------------- radix pass: stable scatter (strip order = memory order) ----------------
__global__ __launch_bounds__(256) void rs_scatter(const u64* __restrict__ kvIn, u64* __restrict__ kvOut,
                                                  const u32* __restrict__ hist, int n, int nblk, int shift) {
  __shared__ u32 sBase[256];
  __shared__ u32 running[256];
  __shared__ u32 waveCnt[4][256];
  int t = threadIdx.x;
  int lane = t & 63, wid = t >> 6;
  int b = blockIdx.x / nblk, blk = blockIdx.x % nblk;
  const u64* kp = kvIn + (size_t)b * n + (size_t)blk * 2048;
  u64 kvr[8]; u32 dg[8];
#pragma unroll
  for (int j = 0; j < 8; ++j) {
    kvr[j] = kp[j * 256 + t];                       // strip j = contiguous 256 items -> stable order
    dg[j] = (u32)(kvr[j] >> (32 + shift)) & 255u;
  }
  sBase[t] = hist[((size_t)b * 256 + t) * nblk + blk];
  running[t] = 0;
  u64 lmask = (1ull << lane) - 1ull;
#pragma unroll
  for (int j = 0; j < 8; ++j) {
    __syncthreads();                                 // order prev strip's reads/update vs zeroing
    waveCnt[0][t] = 0; waveCnt[1][t] = 0; waveCnt[2][t] = 0; waveCnt[3][t] = 0;
    __syncthreads();
    u32 d = dg[j];
    u64 peers = ~0ull;
#pragma unroll
    for (int bit = 0; bit < 8; ++bit) {
      u64 bal = __ballot((d >> bit) & 1);
      peers &= ((d >> bit) & 1) ? bal : ~bal;
    }
    u64 lower = peers & lmask;
    u32 rw = (u32)__popcll(lower);
    bool leader = (lower == 0);
    u32 pcnt = (u32)__popcll(peers);
    if (leader) waveCnt[wid][d] = pcnt;
    __syncthreads();
    u32 pre = running[d];
    for (int w = 0; w < wid; ++w) pre += waveCnt[w][d];
    u32 pos = (u32)b * (u32)n + sBase[d] + pre + rw;
    kvOut[pos] = kvr[j];
    __syncthreads();
    if (leader) atomicAdd(&running[d], pcnt);
  }
}

__global__ void ex_addr(const u64* __restrict__ kv, u32* __restrict__ addr) {
  int i = blockIdx.x * 256 + threadIdx.x;
  addr[i] = (u32)kv[i];
}

// ---------------- conv1 (grouped 1->8, 3x3 SAME) fused with permutation scatter ----------------
// mem layout: [B][N1][8ch] so each scatter is 32B contiguous
__global__ __launch_bounds__(256) void conv1_scatter(const u32* __restrict__ addr, const float* __restrict__ w1,
                                                     const float* __restrict__ b1, float* __restrict__ mem) {
  __shared__ float ax[34][34];
  __shared__ float ws[8][9];
  __shared__ float bs[8];
  int t = threadIdx.x;
  int blk = blockIdx.x;
  int tile = blk & 63; int bk2 = blk >> 6; int k = bk2 % 3; int b = bk2 / 3;
  int ty = tile >> 3, tx = tile & 7;
  if (t < 72) ws[t / 9][t % 9] = w1[k * 72 + t];
  if (t >= 128 && t < 136) bs[t - 128] = b1[k * 8 + (t - 128)];
  const u32* ap = addr + (size_t)b * N1 + (size_t)k * HW_;
  for (int idx = t; idx < 34 * 34; idx += 256) {
    int y = idx / 34, x = idx % 34;
    int h = ty * 32 + y - 1, w = tx * 32 + x - 1;
    float v = 0.f;
    if (h >= 0 && h < 256 && w >= 0 && w < 256) v = (float)ap[h * 256 + w];
    ax[y][x] = v;
  }
  __syncthreads();
  float* mb = mem + (size_t)b * N1 * 8;
#pragma unroll
  for (int s = 0; s < 4; ++s) {
    int p = t + s * 256;
    int y = p >> 5, x = p & 31;
    float f[8];
#pragma unroll
    for (int c = 0; c < 8; ++c) f[c] = bs[c];
#pragma unroll
    for (int dy = 0; dy < 3; ++dy)
#pragma unroll
      for (int dx = 0; dx < 3; ++dx) {
        float v = ax[y + dy][x + dx];
#pragma unroll
        for (int c = 0; c < 8; ++c) f[c] = fmaf(ws[c][dy * 3 + dx], v, f[c]);
      }
    u32 a = (u32)ax[y + 1][x + 1];
    float4* dst = reinterpret_cast<float4*>(mb + (size_t)a * 8);
    float4 lo = make_float4(fmaxf(f[0], 0.f), fmaxf(f[1], 0.f), fmaxf(f[2], 0.f), fmaxf(f[3], 0.f));
    float4 hi = make_float4(fmaxf(f[4], 0.f), fmaxf(f[5], 0.f), fmaxf(f[6], 0.f), fmaxf(f[7], 0.f));
    dst[0] = lo; dst[1] = hi;
  }
}

// ---------------- conv2 (8->16, 3x3 SAME on [24576 x 8]) fused with pool partial sums ----------------
__global__ __launch_bounds__(256) void c2p1(const float* __restrict__ mem, const float* __restrict__ w2,
                                            const float* __restrict__ b2, float* __restrict__ gPartial) {
  __shared__ float tile[98][72];     // 96 rows + halo, pitch 72 to spread banks
  __shared__ float w2s[9][8][16];    // [tap][ci][co]
  __shared__ float b2s[16];
  __shared__ float red[4][4][16];    // [wave][lb][co]
  int blk = blockIdx.x; int sub = blk & 255; int b = blk >> 8;
  int r0 = sub * 96;
  int t = threadIdx.x;
  if (t < 16) b2s[t] = b2[t];
  for (int idx = t; idx < 1152; idx += 256) {
    int co = idx / 72, rem = idx % 72, ci = rem / 9, dd = rem % 9;
    w2s[dd][ci][co] = w2[idx];
  }
  const float* mb = mem + (size_t)b * N1 * 8;
  for (int q = t; q < 98 * 16; q += 256) {
    int rowIdx = q >> 4, rem = q & 15;
    int r = r0 - 1 + rowIdx;
    float4 v = make_float4(0.f, 0.f, 0.f, 0.f);
    if (r >= 0 && r < NROWS_) v = *reinterpret_cast<const float4*>(mb + (size_t)r * 64 + rem * 4);
    *reinterpret_cast<float4*>(&tile[rowIdx][rem * 4]) = v;
  }
  __syncthreads();
  int lanePix = t & 7; int rowoff = t >> 3;   // lane (fixed per thread) / row group
  float acc[3][16];
#pragma unroll
  for (int it = 0; it < 3; ++it)
#pragma unroll
    for (int co = 0; co < 16; ++co) acc[it][co] = 0.f;
#pragma unroll
  for (int dr = 0; dr < 3; ++dr) {
#pragma unroll
    for (int dl = 0; dl < 3; ++dl) {
      int dd = dr * 3 + dl;
      int ll = lanePix + dl - 1;
      bool ok = (ll >= 0) && (ll < 8);
      float va[3][8];
#pragma unroll
      for (int it = 0; it < 3; ++it) {
        int rowIdx = rowoff + 32 * it + dr;
        if (ok) {
          float4 u0 = *reinterpret_cast<const float4*>(&tile[rowIdx][ll * 8]);
          float4 u1 = *reinterpret_cast<const float4*>(&tile[rowIdx][ll * 8 + 4]);
          va[it][0] = u0.x; va[it][1] = u0.y; va[it][2] = u0.z; va[it][3] = u0.w;
          va[it][4] = u1.x; va[it][5] = u1.y; va[it][6] = u1.z; va[it][7] = u1.w;
        } else {
#pragma unroll
          for (int c = 0; c < 8; ++c) va[it][c] = 0.f;
        }
      }
#pragma unroll
      for (int ci = 0; ci < 8; ++ci) {
        const float4* wq = reinterpret_cast<const float4*>(&w2s[dd][ci][0]);
        float4 w0 = wq[0], w1_ = wq[1], w2_ = wq[2], w3_ = wq[3];
#pragma unroll
        for (int it = 0; it < 3; ++it) {
          float v = va[it][ci];
          acc[it][0] = fmaf(w0.x, v, acc[it][0]);   acc[it][1] = fmaf(w0.y, v, acc[it][1]);
          acc[it][2] = fmaf(w0.z, v, acc[it][2]);   acc[it][3] = fmaf(w0.w, v, acc[it][3]);
          acc[it][4] = fmaf(w1_.x, v, acc[it][4]);  acc[it][5] = fmaf(w1_.y, v, acc[it][5]);
          acc[it][6] = fmaf(w1_.z, v, acc[it][6]);  acc[it][7] = fmaf(w1_.w, v, acc[it][7]);
          acc[it][8] = fmaf(w2_.x, v, acc[it][8]);  acc[it][9] = fmaf(w2_.y, v, acc[it][9]);
          acc[it][10] = fmaf(w2_.z, v, acc[it][10]); acc[it][11] = fmaf(w2_.w, v, acc[it][11]);
          acc[it][12] = fmaf(w3_.x, v, acc[it][12]); acc[it][13] = fmaf(w3_.y, v, acc[it][13]);
          acc[it][14] = fmaf(w3_.z, v, acc[it][14]); acc[it][15] = fmaf(w3_.w, v, acc[it][15]);
        }
      }
    }
  }
  float myAcc[16];
#pragma unroll
  for (int co = 0; co < 16; ++co) myAcc[co] = 0.f;
#pragma unroll
  for (int it = 0; it < 3; ++it)
#pragma unroll
    for (int co = 0; co < 16; ++co) myAcc[co] += fmaxf(acc[it][co] + b2s[co], 0.f);
  // butterfly allreduce within lb groups: masks flip bit0 (lane pair) and row-group bits
  const int mk[4] = {1, 8, 16, 32};
#pragma unroll
  for (int m = 0; m < 4; ++m)
#pragma unroll
    for (int co = 0; co < 16; ++co) myAcc[co] += __shfl_xor(myAcc[co], mk[m], 64);
  int lane = t & 63, wid = t >> 6;
  int lb = (lane & 7) >> 1;
  if ((lane & 1) == 0 && lane < 8) {
#pragma unroll
    for (int co = 0; co < 16; ++co) red[wid][lb][co] = myAcc[co];
  }
  __syncthreads();
  if (t < 64) {
    int lb2 = t >> 4, co = t & 15;
    float s = red[0][lb2][co] + red[1][lb2][co] + red[2][lb2][co] + red[3][lb2][co];
    int rb = sub >> 6, subW = sub & 63;
    gPartial[(((size_t)(b * 4 + rb) * 64 + subW) * 64) + lb2 * 16 + co] = s;
  }
}

// deterministic stage-2 reduce -> flat [B][256] (order ch*16 + rb*4 + lb)
__global__ void c2p2(const float* __restrict__ gPartial, float* __restrict__ flatS) {
  int b = blockIdx.x; int t = threadIdx.x;
  int ch = t >> 4; int rb = (t >> 2) & 3; int lb = t & 3;
  float s = 0.f;
  for (int sub = 0; sub < 64; ++sub)
    s += gPartial[(((size_t)(b * 4 + rb) * 64 + sub) * 64) + lb * 16 + ch];
  flatS[b * 256 + t] = s * (1.0f / 12288.0f);
}

// ---------------- projection GEMV: all 8 batches per proj_w read ----------------
__global__ __launch_bounds__(256) void proj_k(const float* __restrict__ flatS, const float* __restrict__ pw,
                                              const float* __restrict__ pb, float* __restrict__ ol) {
  __shared__ float fs[8][256];
  int t = threadIdx.x;
  for (int i = t; i < 2048; i += 256) fs[i >> 8][i & 255] = flatS[i];
  __syncthreads();
  int q = t & 15; int og = t >> 4;
  int o = blockIdx.x * 16 + og;
  float acc[8];
#pragma unroll
  for (int b = 0; b < 8; ++b) acc[b] = 0.f;
  const float* wr = pw + (size_t)o * 256;
#pragma unroll
  for (int j = 0; j < 16; ++j) {
    float w = wr[q + 16 * j];
#pragma unroll
    for (int b = 0; b < 8; ++b) acc[b] = fmaf(fs[b][q + 16 * j], w, acc[b]);
  }
#pragma unroll
  for (int m = 1; m < 16; m <<= 1)
#pragma unroll
    for (int b = 0; b < 8; ++b) acc[b] += __shfl_xor(acc[b], m, 64);
  if (q == 0) {
    float bias = pb[o];
#pragma unroll
    for (int b = 0; b < 8; ++b) ol[(size_t)b * NOPS_ + o] = acc[b] + bias;
  }
}

// ---------------- staged penalty (integer-exact, double accumulation) ----------------
__device__ __forceinline__ double stagedp(float d) {
  double h, base;
  if (d >= 0.f) { h = (double)d; base = h; }
  else { h = (double)(-d); base = h * h; }
  double f = (h <= 2.0) ? 1.0 : (h <= 4.0) ? 1.5 : (h <= 8.0) ? 2.0 : (h <= 16.0) ? 3.0 : 5.0;
  return base * f;
}

__global__ __launch_bounds__(256) void penalty_k(const u64* __restrict__ kv2, const u32* __restrict__ addr,
                                                 double* __restrict__ partials) {
  int b = blockIdx.x >> 6; int blk = blockIdx.x & 63;
  int t = threadIdx.x;
  const u64* pm = kv2 + (size_t)b * NOPS_;
  const u32* ad = addr + (size_t)b * N1;
  double intra = 0.0, inter = 0.0;
#pragma unroll
  for (int s = 0; s < 4; ++s) {
    int tg = blk * 1024 + s * 256 + t;
    u32 p = (u32)pm[tg];
    float a0 = (float)ad[p], a1 = (float)ad[HW_ + p], a2 = (float)ad[2 * HW_ + p];
    intra += stagedp(a1 - a0) + stagedp(a2 - a1);
    if (tg > 0) {
      u32 pp = (u32)pm[tg - 1];
      float a2p = (float)ad[2 * HW_ + pp];
      inter += stagedp(a0 - a2p);
    }
  }
#pragma unroll
  for (int m = 1; m < 64; m <<= 1) {
    intra += __shfl_xor(intra, m, 64);
    inter += __shfl_xor(inter, m, 64);
  }
  __shared__ double red[4][2];
  int lane = t & 63, wid = t >> 6;
  if (lane == 0) { red[wid][0] = inter; red[wid][1] = intra; }
  __syncthreads();
  if (t == 0) {
    double i0 = red[0][0] + red[1][0] + red[2][0] + red[3][0];
    double i1 = red[0][1] + red[1][1] + red[2][1] + red[3][1];
    partials[((size_t)b * 64 + blk) * 2 + 0] = i0;
    partials[((size_t)b * 64 + blk) * 2 + 1] = i1;
  }
}

__global__ void fin_k(const double* __restrict__ partials, float* __restrict__ out) {
  int t = threadIdx.x;
  if (t < 16) {
    int which = t >> 3, b = t & 7;
    double s = 0.0;
    for (int k = 0; k < 64; ++k) s += partials[((size_t)b * 64 + k) * 2 + which];
    out[which * 8 + b] = (float)s;
  }
}

// ---------------- host ----------------
extern "C" void kernel_launch(void* const* d_in, const int* in_sizes, int n_in,
                              void* d_out, int out_size, void* d_ws, size_t ws_size,
                              hipStream_t stream) {
  const float* logits = (const float*)d_in[0];
  const float* w1 = (const float*)d_in[1];
  const float* b1 = (const float*)d_in[2];
  const float* w2 = (const float*)d_in[3];
  const float* b2 = (const float*)d_in[4];
  const float* pw = (const float*)d_in[5];
  const float* pb = (const float*)d_in[6];
  float* out = (float*)d_out;

  char* ws = (char*)d_ws;
  size_t o = 0;
  auto take = [&](size_t bytes) { char* p = ws + o; o += (bytes + 255) & ~(size_t)255; return p; };
  u64* kv1A = (u64*)take((size_t)BN * N1 * 8);
  u64* kv1B = (u64*)take((size_t)BN * N1 * 8);
  u64* kv2A = (u64*)take((size_t)BN * NOPS_ * 8);
  u64* kv2B = (u64*)take((size_t)BN * NOPS_ * 8);
  u32* hist = (u32*)take((size_t)256 * NB1 * BN * 4);
  u32* addr = (u32*)take((size_t)BN * N1 * 4);
  float* mem = (float*)take((size_t)BN * N1 * 8 * 4);
  float* gPartial = (float*)take((size_t)BN * 4 * 64 * 64 * 4);
  float* flatS = (float*)take((size_t)BN * 256 * 4);
  float* ol = (float*)take((size_t)BN * NOPS_ * 4);
  double* partials = (double*)take((size_t)BN * 64 * 2 * 8);

  // sort 1: stable argsort of mem_logits (keys bit-identical to reference)
  bk_kernel<<<BN * N1 / 256, 256, 0, stream>>>(logits, kv1A, N1);
  u64* src = kv1A; u64* dst = kv1B;
  for (int p = 0; p < 4; ++p) {
    rs_hist<<<BN * NB1, 256, 0, stream>>>(src, hist, N1, NB1, p * 8);
    rs_scan<<<BN, 256, 0, stream>>>(hist, NB1);
    rs_scatter<<<BN * NB1, 256, 0, stream>>>(src, dst, hist, N1, NB1, p * 8);
    u64* tmp = src; src = dst; dst = tmp;
  }
  ex_addr<<<BN * N1 / 256, 256, 0, stream>>>(src, addr);

  // conv1 + permutation scatter into mem [B][N1][8]
  conv1_scatter<<<BN * 3 * 64, 256, 0, stream>>>(addr, w1, b1, mem);

  // conv2 + adaptive pool (two-stage deterministic reduction)
  c2p1<<<BN * 256, 256, 0, stream>>>(mem, w2, b2, gPartial);
  c2p2<<<BN, 256, 0, stream>>>(gPartial, flatS);

  // projection GEMV
  proj_k<<<NOPS_ / 16, 256, 0, stream>>>(flatS, pw, pb, ol);

  // sort 2: stable argsort of op_logits
  bk_kernel<<<BN * NOPS_ / 256, 256, 0, stream>>>(ol, kv2A, NOPS_);
  src = kv2A; dst = kv2B;
  for (int p = 0; p < 4; ++p) {
    rs_hist<<<BN * NB2, 256, 0, stream>>>(src, hist, NOPS_, NB2, p * 8);
    rs_scan<<<BN, 256, 0, stream>>>(hist, NB2);
    rs_scatter<<<BN * NB2, 256, 0, stream>>>(src, dst, hist, NOPS_, NB2, p * 8);
    u64* tmp = src; src = dst; dst = tmp;
  }

  // staged penalties
  penalty_k<<<BN * 64, 256, 0, stream>>>(src, addr, partials);
  fin_k<<<1, 64, 0, stream>>>(partials, out);
}

// Round 2
// 481.007 us; speedup vs baseline: 2.4525x; 2.4525x over previous
//
#include <hip/hip_runtime.h>
#include <stdint.h>

typedef unsigned int u32;
typedef unsigned long long u64;

#define BN 8
#define HW_ 65536
#define N1 196608
#define NOPS_ 65536
#define NROWS_ 24576
#define NB1 96
#define NB2 32

// ---------------- sort: key transform + build packed (key|idx) ----------------
__device__ __forceinline__ u32 fkey(float x) {
  u32 u = __float_as_uint(x);
  return u ^ ((u & 0x80000000u) ? 0xFFFFFFFFu : 0x80000000u);
}

__global__ void bk_kernel(const float* __restrict__ x, u64* __restrict__ kv, int n) {
  int i = blockIdx.x * 256 + threadIdx.x;
  u32 k = fkey(x[i]);
  kv[i] = ((u64)k << 32) | (u32)(i % n);
}

// ---------------- radix pass: histogram ----------------
__global__ __launch_bounds__(256) void rs_hist(const u64* __restrict__ kv, u32* __restrict__ hist,
                                               int n, int nblk, int shift) {
  __shared__ u32 h[256];
  int t = threadIdx.x;
  int b = blockIdx.x / nblk, blk = blockIdx.x % nblk;
  h[t] = 0;
  __syncthreads();
  const u64* kp = kv + (size_t)b * n + (size_t)blk * 2048;
#pragma unroll
  for (int j = 0; j < 8; ++j) {
    u32 d = (u32)(kp[j * 256 + t] >> (32 + shift)) & 255u;
    atomicAdd(&h[d], 1u);
  }
  __syncthreads();
  hist[((size_t)b * 256 + t) * nblk + blk] = h[t];
}

// ---------------- radix pass: per-batch exclusive scan (digit-major) ----------------
__global__ __launch_bounds__(256) void rs_scan(u32* __restrict__ hist, int nblk) {
  __shared__ u32 sums[256];
  int b = blockIdx.x, t = threadIdx.x;
  u32* p = hist + (size_t)b * 256 * nblk;
  u32 s = 0;
  for (int j = 0; j < nblk; ++j) s += p[t * nblk + j];
  sums[t] = s;
  __syncthreads();
  for (int off = 1; off < 256; off <<= 1) {
    u32 v = (t >= off) ? sums[t - off] : 0u;
    __syncthreads();
    sums[t] += v;
    __syncthreads();
  }
  u32 run = (t == 0) ? 0u : sums[t - 1];
  for (int j = 0; j < nblk; ++j) { u32 c = p[t * nblk + j]; p[t * nblk + j] = run; run += c; }
}

// ---------------- radix pass: stable scatter (strip order = memory order) ----------------
__global__ __launch_bounds__(256) void rs_scatter(const u64* __restrict__ kvIn, u64* __restrict__ kvOut,
                                                  const u32* __restrict__ hist, int n, int nblk, int shift) {
  __shared__ u32 sBase[256];
  __shared__ u32 running[256];
  __shared__ u32 waveCnt[4][256];
  int t = threadIdx.x;
  int lane = t & 63, wid = t >> 6;
  int b = blockIdx.x / nblk, blk = blockIdx.x % nblk;
  const u64* kp = kvIn + (size_t)b * n + (size_t)blk * 2048;
  u64 kvr[8]; u32 dg[8];
#pragma unroll
  for (int j = 0; j < 8; ++j) {
    kvr[j] = kp[j * 256 + t];                       // strip j = contiguous 256 items -> stable order
    dg[j] = (u32)(kvr[j] >> (32 + shift)) & 255u;
  }
  sBase[t] = hist[((size_t)b * 256 + t) * nblk + blk];
  running[t] = 0;
  u64 lmask = (1ull << lane) - 1ull;
#pragma unroll
  for (int j = 0; j < 8; ++j) {
    __syncthreads();                                 // order prev strip's reads/update vs zeroing
    waveCnt[0][t] = 0; waveCnt[1][t] = 0; waveCnt[2][t] = 0; waveCnt[3][t] = 0;
    __syncthreads();
    u32 d = dg[j];
    u64 peers = ~0ull;
#pragma unroll
    for (int bit = 0; bit < 8; ++bit) {
      u64 bal = __ballot((d >> bit) & 1);
      peers &= ((d >> bit) & 1) ? bal : ~bal;
    }
    u64 lower = peers & lmask;
    u32 rw = (u32)__popcll(lower);
    bool leader = (lower == 0);
    u32 pcnt = (u32)__popcll(peers);
    if (leader) waveCnt[wid][d] = pcnt;
    __syncthreads();
    u32 pre = running[d];
    for (int w = 0; w < wid; ++w) pre += waveCnt[w][d];
    u32 pos = (u32)b * (u32)n + sBase[d] + pre + rw;
    kvOut[pos] = kvr[j];
    __syncthreads();
    if (leader) atomicAdd(&running[d], pcnt);
  }
}

__global__ void ex_addr(const u64* __restrict__ kv, u32* __restrict__ addr) {
  int i = blockIdx.x * 256 + threadIdx.x;
  addr[i] = (u32)kv[i];
}

// ---------------- conv1 (grouped 1->8, 3x3 SAME) fused with permutation scatter ----------------
// mem layout: [B][N1][8ch] so each scatter is 32B contiguous
__global__ __launch_bounds__(256) void conv1_scatter(const u32* __restrict__ addr, const float* __restrict__ w1,
                                                     const float* __restrict__ b1, float* __restrict__ mem) {
  __shared__ float ax[34][34];
  __shared__ float ws[8][9];
  __shared__ float bs[8];
  int t = threadIdx.x;
  int blk = blockIdx.x;
  int tile = blk & 63; int bk2 = blk >> 6; int k = bk2 % 3; int b = bk2 / 3;
  int ty = tile >> 3, tx = tile & 7;
  if (t < 72) ws[t / 9][t % 9] = w1[k * 72 + t];
  if (t >= 128 && t < 136) bs[t - 128] = b1[k * 8 + (t - 128)];
  const u32* ap = addr + (size_t)b * N1 + (size_t)k * HW_;
  for (int idx = t; idx < 34 * 34; idx += 256) {
    int y = idx / 34, x = idx % 34;
    int h = ty * 32 + y - 1, w = tx * 32 + x - 1;
    float v = 0.f;
    if (h >= 0 && h < 256 && w >= 0 && w < 256) v = (float)ap[h * 256 + w];
    ax[y][x] = v;
  }
  __syncthreads();
  float* mb = mem + (size_t)b * N1 * 8;
#pragma unroll
  for (int s = 0; s < 4; ++s) {
    int p = t + s * 256;
    int y = p >> 5, x = p & 31;
    float f[8];
#pragma unroll
    for (int c = 0; c < 8; ++c) f[c] = bs[c];
#pragma unroll
    for (int dy = 0; dy < 3; ++dy)
#pragma unroll
      for (int dx = 0; dx < 3; ++dx) {
        float v = ax[y + dy][x + dx];
#pragma unroll
        for (int c = 0; c < 8; ++c) f[c] = fmaf(ws[c][dy * 3 + dx], v, f[c]);
      }
    u32 a = (u32)ax[y + 1][x + 1];
    float4* dst = reinterpret_cast<float4*>(mb + (size_t)a * 8);
    float4 lo = make_float4(fmaxf(f[0], 0.f), fmaxf(f[1], 0.f), fmaxf(f[2], 0.f), fmaxf(f[3], 0.f));
    float4 hi = make_float4(fmaxf(f[4], 0.f), fmaxf(f[5], 0.f), fmaxf(f[6], 0.f), fmaxf(f[7], 0.f));
    dst[0] = lo; dst[1] = hi;
  }
}

// ---------------- conv2 (8->16, 3x3 SAME on [24576 x 8]) fused with pool partial sums ----------------
// v2: co split across lanes (co = t&15), weights in registers, 2 rows/thread.
// LDS tile pitch 68 words: wave's 4 rowgrps are 2 rows apart -> 136 words = 8 mod 32 banks
// -> disjoint bank quads, conflict-free broadcast reads.
__global__ __launch_bounds__(256, 3) void c2p1(const float* __restrict__ mem, const float* __restrict__ w2,
                                               const float* __restrict__ b2, float* __restrict__ gPartial) {
  __shared__ float tile[98 * 68];
  __shared__ float w2s[1152];
  __shared__ float b2s[16];
  __shared__ float red[16][64];   // [rowgrp][lb*16+co]
  int blk = blockIdx.x; int sub = blk & 255; int b = blk >> 8;
  int r0 = sub * 96;
  int t = threadIdx.x;
  for (int idx = t; idx < 1152; idx += 256) w2s[idx] = w2[idx];
  if (t < 16) b2s[t] = b2[t];
  const float* mb = mem + (size_t)b * (N1 * 8);
  for (int q = t; q < 98 * 16; q += 256) {
    int ti = q >> 4, qw = q & 15;
    int r = r0 - 1 + ti;
    float4 v = make_float4(0.f, 0.f, 0.f, 0.f);
    if (r >= 0 && r < NROWS_) v = *reinterpret_cast<const float4*>(mb + (size_t)r * 64 + qw * 4);
    *reinterpret_cast<float4*>(&tile[ti * 68 + qw * 4]) = v;
  }
  __syncthreads();
  int co = t & 15, rowgrp = t >> 4;
  float wreg[3][3][8];
#pragma unroll
  for (int ci = 0; ci < 8; ++ci)
#pragma unroll
    for (int kr = 0; kr < 3; ++kr)
#pragma unroll
      for (int kc = 0; kc < 3; ++kc)
        wreg[kr][kc][ci] = w2s[(co * 8 + ci) * 9 + kr * 3 + kc];
  float bias = b2s[co];
  float pool[4] = {0.f, 0.f, 0.f, 0.f};
#pragma unroll 1
  for (int i = 0; i < 3; ++i) {
    int lr0 = rowgrp * 2 + 32 * i;     // local output row pair (lr0, lr0+1)
    float s0[8], s1[8];
#pragma unroll
    for (int l = 0; l < 8; ++l) { s0[l] = 0.f; s1[l] = 0.f; }
#pragma unroll
    for (int j = 0; j < 4; ++j) {      // input tile rows lr0 .. lr0+3
      const float* trow = &tile[(lr0 + j) * 68];
#pragma unroll
      for (int li = 0; li < 8; ++li) { // input lane
        float4 aa = *reinterpret_cast<const float4*>(trow + li * 8);
        float4 bb = *reinterpret_cast<const float4*>(trow + li * 8 + 4);
        float in[8] = {aa.x, aa.y, aa.z, aa.w, bb.x, bb.y, bb.z, bb.w};
#pragma unroll
        for (int ci = 0; ci < 8; ++ci) {
          float v = in[ci];
          if (j < 3) {                 // contributes to output row lr0 with kr = j
            if (li >= 1) s0[li - 1] = fmaf(v, wreg[j][2][ci], s0[li - 1]);
            s0[li] = fmaf(v, wreg[j][1][ci], s0[li]);
            if (li < 7) s0[li + 1] = fmaf(v, wreg[j][0][ci], s0[li + 1]);
          }
          if (j >= 1) {                // contributes to output row lr0+1 with kr = j-1
            if (li >= 1) s1[li - 1] = fmaf(v, wreg[j - 1][2][ci], s1[li - 1]);
            s1[li] = fmaf(v, wreg[j - 1][1][ci], s1[li]);
            if (li < 7) s1[li + 1] = fmaf(v, wreg[j - 1][0][ci], s1[li + 1]);
          }
        }
      }
    }
#pragma unroll
    for (int l = 0; l < 8; ++l)
      pool[l >> 1] += fmaxf(s0[l] + bias, 0.f) + fmaxf(s1[l] + bias, 0.f);
  }
#pragma unroll
  for (int lb = 0; lb < 4; ++lb) red[rowgrp][lb * 16 + co] = pool[lb];
  __syncthreads();
  if (t < 64) {
    float s = 0.f;
#pragma unroll
    for (int rg = 0; rg < 16; ++rg) s += red[rg][t];
    int rb = sub >> 6, subW = sub & 63;
    gPartial[(((size_t)(b * 4 + rb) * 64 + subW) * 64) + t] = s;
  }
}

// deterministic stage-2 reduce -> flat [B][256] (order ch*16 + rb*4 + lb)
__global__ void c2p2(const float* __restrict__ gPartial, float* __restrict__ flatS) {
  int b = blockIdx.x; int t = threadIdx.x;
  int ch = t >> 4; int rb = (t >> 2) & 3; int lb = t & 3;
  float s = 0.f;
  for (int sub = 0; sub < 64; ++sub)
    s += gPartial[(((size_t)(b * 4 + rb) * 64 + sub) * 64) + lb * 16 + ch];
  flatS[b * 256 + t] = s * (1.0f / 12288.0f);
}

// ---------------- projection GEMV: all 8 batches per proj_w read ----------------
__global__ __launch_bounds__(256) void proj_k(const float* __restrict__ flatS, const float* __restrict__ pw,
                                              const float* __restrict__ pb, float* __restrict__ ol) {
  __shared__ float fs[8][256];
  int t = threadIdx.x;
  for (int i = t; i < 2048; i += 256) fs[i >> 8][i & 255] = flatS[i];
  __syncthreads();
  int q = t & 15; int og = t >> 4;
  int o = blockIdx.x * 16 + og;
  float acc[8];
#pragma unroll
  for (int b = 0; b < 8; ++b) acc[b] = 0.f;
  const float* wr = pw + (size_t)o * 256;
#pragma unroll
  for (int j = 0; j < 16; ++j) {
    float w = wr[q + 16 * j];
#pragma unroll
    for (int b = 0; b < 8; ++b) acc[b] = fmaf(fs[b][q + 16 * j], w, acc[b]);
  }
#pragma unroll
  for (int m = 1; m < 16; m <<= 1)
#pragma unroll
    for (int b = 0; b < 8; ++b) acc[b] += __shfl_xor(acc[b], m, 64);
  if (q == 0) {
    float bias = pb[o];
#pragma unroll
    for (int b = 0; b < 8; ++b) ol[(size_t)b * NOPS_ + o] = acc[b] + bias;
  }
}

// ---------------- staged penalty (integer-exact, double accumulation) ----------------
__device__ __forceinline__ double stagedp(float d) {
  double h, base;
  if (d >= 0.f) { h = (double)d; base = h; }
  else { h = (double)(-d); base = h * h; }
  double f = (h <= 2.0) ? 1.0 : (h <= 4.0) ? 1.5 : (h <= 8.0) ? 2.0 : (h <= 16.0) ? 3.0 : 5.0;
  return base * f;
}

__global__ __launch_bounds__(256) void penalty_k(const u64* __restrict__ kv2, const u32* __restrict__ addr,
                                                 double* __restrict__ partials) {
  int b = blockIdx.x >> 6; int blk = blockIdx.x & 63;
  int t = threadIdx.x;
  const u64* pm = kv2 + (size_t)b * NOPS_;
  const u32* ad = addr + (size_t)b * N1;
  double intra = 0.0, inter = 0.0;
#pragma unroll
  for (int s = 0; s < 4; ++s) {
    int tg = blk * 1024 + s * 256 + t;
    u32 p = (u32)pm[tg];
    float a0 = (float)ad[p], a1 = (float)ad[HW_ + p], a2 = (float)ad[2 * HW_ + p];
    intra += stagedp(a1 - a0) + stagedp(a2 - a1);
    if (tg > 0) {
      u32 pp = (u32)pm[tg - 1];
      float a2p = (float)ad[2 * HW_ + pp];
      inter += stagedp(a0 - a2p);
    }
  }
#pragma unroll
  for (int m = 1; m < 64; m <<= 1) {
    intra += __shfl_xor(intra, m, 64);
    inter += __shfl_xor(inter, m, 64);
  }
  __shared__ double red[4][2];
  int lane = t & 63, wid = t >> 6;
  if (lane == 0) { red[wid][0] = inter; red[wid][1] = intra; }
  __syncthreads();
  if (t == 0) {
    double i0 = red[0][0] + red[1][0] + red[2][0] + red[3][0];
    double i1 = red[0][1] + red[1][1] + red[2][1] + red[3][1];
    partials[((size_t)b * 64 + blk) * 2 + 0] = i0;
    partials[((size_t)b * 64 + blk) * 2 + 1] = i1;
  }
}

__global__ void fin_k(const double* __restrict__ partials, float* __restrict__ out) {
  int t = threadIdx.x;
  if (t < 16) {
    int which = t >> 3, b = t & 7;
    double s = 0.0;
    for (int k = 0; k < 64; ++k) s += partials[((size_t)b * 64 + k) * 2 + which];
    out[which * 8 + b] = (float)s;
  }
}

// ---------------- host ----------------
extern "C" void kernel_launch(void* const* d_in, const int* in_sizes, int n_in,
                              void* d_out, int out_size, void* d_ws, size_t ws_size,
                              hipStream_t stream) {
  const float* logits = (const float*)d_in[0];
  const float* w1 = (const float*)d_in[1];
  const float* b1 = (const float*)d_in[2];
  const float* w2 = (const float*)d_in[3];
  const float* b2 = (const float*)d_in[4];
  const float* pw = (const float*)d_in[5];
  const float* pb = (const float*)d_in[6];
  float* out = (float*)d_out;

  char* ws = (char*)d_ws;
  size_t o = 0;
  auto take = [&](size_t bytes) { char* p = ws + o; o += (bytes + 255) & ~(size_t)255; return p; };
  u64* kv1A = (u64*)take((size_t)BN * N1 * 8);
  u64* kv1B = (u64*)take((size_t)BN * N1 * 8);
  u64* kv2A = (u64*)take((size_t)BN * NOPS_ * 8);
  u64* kv2B = (u64*)take((size_t)BN * NOPS_ * 8);
  u32* hist = (u32*)take((size_t)256 * NB1 * BN * 4);
  u32* addr = (u32*)take((size_t)BN * N1 * 4);
  float* mem = (float*)take((size_t)BN * N1 * 8 * 4);
  float* gPartial = (float*)take((size_t)BN * 4 * 64 * 64 * 4);
  float* flatS = (float*)take((size_t)BN * 256 * 4);
  float* ol = (float*)take((size_t)BN * NOPS_ * 4);
  double* partials = (double*)take((size_t)BN * 64 * 2 * 8);

  // sort 1: stable argsort of mem_logits (keys bit-identical to reference)
  bk_kernel<<<BN * N1 / 256, 256, 0, stream>>>(logits, kv1A, N1);
  u64* src = kv1A; u64* dst = kv1B;
  for (int p = 0; p < 4; ++p) {
    rs_hist<<<BN * NB1, 256, 0, stream>>>(src, hist, N1, NB1, p * 8);
    rs_scan<<<BN, 256, 0, stream>>>(hist, NB1);
    rs_scatter<<<BN * NB1, 256, 0, stream>>>(src, dst, hist, N1, NB1, p * 8);
    u64* tmp = src; src = dst; dst = tmp;
  }
  ex_addr<<<BN * N1 / 256, 256, 0, stream>>>(src, addr);

  // conv1 + permutation scatter into mem [B][N1][8]
  conv1_scatter<<<BN * 3 * 64, 256, 0, stream>>>(addr, w1, b1, mem);

  // conv2 + adaptive pool (two-stage deterministic reduction)
  c2p1<<<BN * 256, 256, 0, stream>>>(mem, w2, b2, gPartial);
  c2p2<<<BN, 256, 0, stream>>>(gPartial, flatS);

  // projection GEMV
  proj_k<<<NOPS_ / 16, 256, 0, stream>>>(flatS, pw, pb, ol);

  // sort 2: stable argsort of op_logits
  bk_kernel<<<BN * NOPS_ / 256, 256, 0, stream>>>(ol, kv2A, NOPS_);
  src = kv2A; dst = kv2B;
  for (int p = 0; p < 4; ++p) {
    rs_hist<<<BN * NB2, 256, 0, stream>>>(src, hist, NOPS_, NB2, p * 8);
    rs_scan<<<BN, 256, 0, stream>>>(hist, NB2);
    rs_scatter<<<BN * NB2, 256, 0, stream>>>(src, dst, hist, NOPS_, NB2, p * 8);
    u64* tmp = src; src = dst; dst = tmp;
  }

  // staged penalties
  penalty_k<<<BN * 64, 256, 0, stream>>>(src, addr, partials);
  fin_k<<<1, 64, 0, stream>>>(partials, out);
}

// Round 3
// 443.105 us; speedup vs baseline: 2.6623x; 1.0855x over previous
//
#include <hip/hip_runtime.h>
#include <stdint.h>

typedef unsigned int u32;
typedef unsigned long long u64;

#define BN 8
#define HW_ 65536
#define N1 196608
#define NOPS_ 65536
#define NROWS_ 24576
#define NB1 192
#define NB2 64

// ---------------- sort: key transform + build packed (key|idx) ----------------
__device__ __forceinline__ u32 fkey(float x) {
  u32 u = __float_as_uint(x);
  return u ^ ((u & 0x80000000u) ? 0xFFFFFFFFu : 0x80000000u);
}

__global__ void bk_kernel(const float* __restrict__ x, u64* __restrict__ kv, int n) {
  int i = blockIdx.x * 256 + threadIdx.x;
  u32 k = fkey(x[i]);
  kv[i] = ((u64)k << 32) | (u32)(i % n);
}

// ---------------- radix pass: histogram (1024 items/block, 4 strips) ----------------
__global__ __launch_bounds__(256) void rs_hist(const u64* __restrict__ kv, u32* __restrict__ hist,
                                               int n, int nblk, int shift) {
  __shared__ u32 h[256];
  int t = threadIdx.x;
  int b = blockIdx.x / nblk, blk = blockIdx.x % nblk;
  h[t] = 0;
  __syncthreads();
  const u64* kp = kv + (size_t)b * n + (size_t)blk * 1024;
#pragma unroll
  for (int j = 0; j < 4; ++j) {
    u32 d = (u32)(kp[j * 256 + t] >> (32 + shift)) & 255u;
    atomicAdd(&h[d], 1u);
  }
  __syncthreads();
  hist[((size_t)b * 256 + t) * nblk + blk] = h[t];
}

// ---------------- wave-parallel scan: per-digit block-offsets + digit bases ----------------
__device__ __forceinline__ u32 wscan_incl(u32 x, int lane) {
#pragma unroll
  for (int off = 1; off < 64; off <<= 1) {
    u32 y = __shfl_up(x, off, 64);
    if (lane >= off) x += y;
  }
  return x;
}

__global__ __launch_bounds__(1024) void rs_scan(u32* __restrict__ hist, u32* __restrict__ dBase, int nblk) {
  __shared__ u32 dt[256];
  int b = blockIdx.x;
  int t = threadIdx.x, w = t >> 6, lane = t & 63;
#pragma unroll 1
  for (int dd = 0; dd < 16; ++dd) {
    int d = w * 16 + dd;
    u32* p = hist + ((size_t)b * 256 + d) * nblk;
    u32 run = 0;
    for (int c = 0; c < nblk; c += 64) {
      u32 v = p[c + lane];
      u32 inc = wscan_incl(v, lane);
      p[c + lane] = run + inc - v;
      run += __shfl(inc, 63, 64);
    }
    if (lane == 0) dt[d] = run;
  }
  __syncthreads();
  if (w == 0) {
    u32 run = 0;
#pragma unroll
    for (int c = 0; c < 256; c += 64) {
      u32 v = dt[c + lane];
      u32 inc = wscan_incl(v, lane);
      dBase[b * 256 + c + lane] = run + inc - v;
      run += __shfl(inc, 63, 64);
    }
  }
}

// ---------------- radix pass: stable scatter (4 strips, 3 barriers/strip) ----------------
template <bool FINAL>
__global__ __launch_bounds__(256) void rs_scatter(const u64* __restrict__ kvIn, u64* __restrict__ out64,
                                                  u32* __restrict__ out32, const u32* __restrict__ hist,
                                                  const u32* __restrict__ dBase, int n, int nblk, int shift) {
  __shared__ u32 sBase[256];
  __shared__ u32 running[256];
  __shared__ u32 waveCnt[4][256];
  int t = threadIdx.x;
  int lane = t & 63, wid = t >> 6;
  int b = blockIdx.x / nblk, blk = blockIdx.x % nblk;
  const u64* kp = kvIn + (size_t)b * n + (size_t)blk * 1024;
  u64 kvr[4]; u32 dg[4];
#pragma unroll
  for (int j = 0; j < 4; ++j) {
    kvr[j] = kp[j * 256 + t];
    dg[j] = (u32)(kvr[j] >> (32 + shift)) & 255u;
  }
  sBase[t] = hist[((size_t)b * 256 + t) * nblk + blk] + dBase[b * 256 + t];
  running[t] = 0;
  waveCnt[0][t] = 0; waveCnt[1][t] = 0; waveCnt[2][t] = 0; waveCnt[3][t] = 0;
  u64 lmask = (1ull << lane) - 1ull;
  __syncthreads();
#pragma unroll
  for (int j = 0; j < 4; ++j) {
    u32 d = dg[j];
    u64 peers = ~0ull;
#pragma unroll
    for (int bit = 0; bit < 8; ++bit) {
      u64 bal = __ballot((d >> bit) & 1);
      peers &= ((d >> bit) & 1) ? bal : ~bal;
    }
    u64 lower = peers & lmask;
    u32 rw = (u32)__popcll(lower);
    bool leader = (lower == 0);
    u32 pcnt = (u32)__popcll(peers);
    if (leader) waveCnt[wid][d] = pcnt;
    __syncthreads();
    u32 pre = running[d];
    for (int w = 0; w < wid; ++w) pre += waveCnt[w][d];
    u32 pos = sBase[d] + pre + rw;
    if (FINAL) out32[(size_t)b * n + pos] = (u32)kvr[j];
    else out64[(size_t)b * n + pos] = kvr[j];
    __syncthreads();
    running[t] += waveCnt[0][t] + waveCnt[1][t] + waveCnt[2][t] + waveCnt[3][t];
    waveCnt[0][t] = 0; waveCnt[1][t] = 0; waveCnt[2][t] = 0; waveCnt[3][t] = 0;
    if (j < 3) __syncthreads();
  }
}

// ---------------- conv1 (grouped 1->8, 3x3 SAME) fused with permutation scatter ----------------
__global__ __launch_bounds__(256) void conv1_scatter(const u32* __restrict__ addr, const float* __restrict__ w1,
                                                     const float* __restrict__ b1, float* __restrict__ mem) {
  __shared__ float ax[34][34];
  __shared__ float ws[8][9];
  __shared__ float bs[8];
  int t = threadIdx.x;
  int blk = blockIdx.x;
  int tile = blk & 63; int bk2 = blk >> 6; int k = bk2 % 3; int b = bk2 / 3;
  int ty = tile >> 3, tx = tile & 7;
  if (t < 72) ws[t / 9][t % 9] = w1[k * 72 + t];
  if (t >= 128 && t < 136) bs[t - 128] = b1[k * 8 + (t - 128)];
  const u32* ap = addr + (size_t)b * N1 + (size_t)k * HW_;
  for (int idx = t; idx < 34 * 34; idx += 256) {
    int y = idx / 34, x = idx % 34;
    int h = ty * 32 + y - 1, w = tx * 32 + x - 1;
    float v = 0.f;
    if (h >= 0 && h < 256 && w >= 0 && w < 256) v = (float)ap[h * 256 + w];
    ax[y][x] = v;
  }
  __syncthreads();
  float* mb = mem + (size_t)b * N1 * 8;
#pragma unroll
  for (int s = 0; s < 4; ++s) {
    int p = t + s * 256;
    int y = p >> 5, x = p & 31;
    float f[8];
#pragma unroll
    for (int c = 0; c < 8; ++c) f[c] = bs[c];
#pragma unroll
    for (int dy = 0; dy < 3; ++dy)
#pragma unroll
      for (int dx = 0; dx < 3; ++dx) {
        float v = ax[y + dy][x + dx];
#pragma unroll
        for (int c = 0; c < 8; ++c) f[c] = fmaf(ws[c][dy * 3 + dx], v, f[c]);
      }
    u32 a = (u32)ax[y + 1][x + 1];
    float4* dst = reinterpret_cast<float4*>(mb + (size_t)a * 8);
    float4 lo = make_float4(fmaxf(f[0], 0.f), fmaxf(f[1], 0.f), fmaxf(f[2], 0.f), fmaxf(f[3], 0.f));
    float4 hi = make_float4(fmaxf(f[4], 0.f), fmaxf(f[5], 0.f), fmaxf(f[6], 0.f), fmaxf(f[7], 0.f));
    dst[0] = lo; dst[1] = hi;
  }
}

// ---------------- conv2 + pool: ci-chunked weights (36 regs resident) ----------------
__global__ __launch_bounds__(256) void c2p1(const float* __restrict__ mem, const float* __restrict__ w2,
                                            const float* __restrict__ b2, float* __restrict__ gPartial) {
  __shared__ float tile[98 * 68];
  __shared__ float w2t[16 * 9 * 8];   // [co][tap][ci]
  __shared__ float b2s[16];
  __shared__ float red[16][64];
  int blk = blockIdx.x; int sub = blk & 255; int b = blk >> 8;
  int r0 = sub * 96;
  int t = threadIdx.x;
  for (int idx = t; idx < 1152; idx += 256) {
    int co = idx / 72, rem = idx % 72, tap = rem >> 3, ci = rem & 7;
    w2t[idx] = w2[(co * 8 + ci) * 9 + tap];
  }
  if (t < 16) b2s[t] = b2[t];
  const float* mb = mem + (size_t)b * (N1 * 8);
  for (int q = t; q < 98 * 16; q += 256) {
    int ti = q >> 4, qw = q & 15;
    int r = r0 - 1 + ti;
    float4 v = make_float4(0.f, 0.f, 0.f, 0.f);
    if (r >= 0 && r < NROWS_) v = *reinterpret_cast<const float4*>(mb + (size_t)r * 64 + qw * 4);
    *reinterpret_cast<float4*>(&tile[ti * 68 + qw * 4]) = v;
  }
  __syncthreads();
  int co = t & 15, rowgrp = t >> 4;
  const float* wbase = &w2t[co * 72];
  float bias = b2s[co];
  float pool[4] = {0.f, 0.f, 0.f, 0.f};
#pragma unroll 1
  for (int i = 0; i < 3; ++i) {
    int lr0 = rowgrp * 2 + 32 * i;
    float s0[8], s1[8];
#pragma unroll
    for (int l = 0; l < 8; ++l) { s0[l] = 0.f; s1[l] = 0.f; }
#pragma unroll 1
    for (int ch = 0; ch < 2; ++ch) {
      float4 wq[9];
#pragma unroll
      for (int tap = 0; tap < 9; ++tap)
        wq[tap] = *reinterpret_cast<const float4*>(wbase + tap * 8 + ch * 4);
#pragma unroll
      for (int j = 0; j < 4; ++j) {
        const float* trow = &tile[(lr0 + j) * 68 + ch * 4];
#pragma unroll
        for (int li = 0; li < 8; ++li) {
          float4 v = *reinterpret_cast<const float4*>(trow + li * 8);
#pragma unroll
          for (int c = 0; c < 4; ++c) {
            float x = (&v.x)[c];
            if (j < 3) {
              if (li >= 1) s0[li - 1] = fmaf(x, (&wq[j * 3 + 2].x)[c], s0[li - 1]);
              s0[li] = fmaf(x, (&wq[j * 3 + 1].x)[c], s0[li]);
              if (li < 7) s0[li + 1] = fmaf(x, (&wq[j * 3 + 0].x)[c], s0[li + 1]);
            }
            if (j >= 1) {
              if (li >= 1) s1[li - 1] = fmaf(x, (&wq[(j - 1) * 3 + 2].x)[c], s1[li - 1]);
              s1[li] = fmaf(x, (&wq[(j - 1) * 3 + 1].x)[c], s1[li]);
              if (li < 7) s1[li + 1] = fmaf(x, (&wq[(j - 1) * 3 + 0].x)[c], s1[li + 1]);
            }
          }
        }
      }
    }
#pragma unroll
    for (int l = 0; l < 8; ++l)
      pool[l >> 1] += fmaxf(s0[l] + bias, 0.f) + fmaxf(s1[l] + bias, 0.f);
  }
#pragma unroll
  for (int lb = 0; lb < 4; ++lb) red[rowgrp][lb * 16 + co] = pool[lb];
  __syncthreads();
  if (t < 64) {
    float s = 0.f;
#pragma unroll
    for (int rg = 0; rg < 16; ++rg) s += red[rg][t];
    int rb = sub >> 6, subW = sub & 63;
    gPartial[(((size_t)(b * 4 + rb) * 64 + subW) * 64) + t] = s;
  }
}

// deterministic stage-2 reduce -> flat [B][256] (order ch*16 + rb*4 + lb)
__global__ void c2p2(const float* __restrict__ gPartial, float* __restrict__ flatS) {
  int b = blockIdx.x; int t = threadIdx.x;
  int ch = t >> 4; int rb = (t >> 2) & 3; int lb = t & 3;
  float s = 0.f;
  for (int sub = 0; sub < 64; ++sub)
    s += gPartial[(((size_t)(b * 4 + rb) * 64 + sub) * 64) + lb * 16 + ch];
  flatS[b * 256 + t] = s * (1.0f / 12288.0f);
}

// ---------------- projection GEMV fused with sort-2 key build ----------------
__global__ __launch_bounds__(256) void proj_k(const float* __restrict__ flatS, const float* __restrict__ pw,
                                              const float* __restrict__ pb, u64* __restrict__ kv2) {
  __shared__ float fs[8][256];
  int t = threadIdx.x;
  for (int i = t; i < 2048; i += 256) fs[i >> 8][i & 255] = flatS[i];
  __syncthreads();
  int q = t & 15; int og = t >> 4;
  int o = blockIdx.x * 16 + og;
  float acc[8];
#pragma unroll
  for (int b = 0; b < 8; ++b) acc[b] = 0.f;
  const float* wr = pw + (size_t)o * 256;
#pragma unroll
  for (int j = 0; j < 16; ++j) {
    float w = wr[q + 16 * j];
#pragma unroll
    for (int b = 0; b < 8; ++b) acc[b] = fmaf(fs[b][q + 16 * j], w, acc[b]);
  }
#pragma unroll
  for (int m = 1; m < 16; m <<= 1)
#pragma unroll
    for (int b = 0; b < 8; ++b) acc[b] += __shfl_xor(acc[b], m, 64);
  if (q == 0) {
    float bias = pb[o];
#pragma unroll
    for (int b = 0; b < 8; ++b) {
      u32 k = fkey(acc[b] + bias);
      kv2[(size_t)b * NOPS_ + o] = ((u64)k << 32) | (u32)o;
    }
  }
}

// ---------------- interleaved addr table for penalty gathers ----------------
__global__ void addr3_k(const u32* __restrict__ addr, uint4* __restrict__ addr3) {
  int i = blockIdx.x * 256 + threadIdx.x;
  int b = i >> 16, p = i & (HW_ - 1);
  const u32* ad = addr + (size_t)b * N1;
  addr3[(size_t)b * HW_ + p] = make_uint4(ad[p], ad[HW_ + p], ad[2 * HW_ + p], 0u);
}

// ---------------- staged penalty (integer-exact, double accumulation) ----------------
__device__ __forceinline__ double stagedp(float d) {
  double h, base;
  if (d >= 0.f) { h = (double)d; base = h; }
  else { h = (double)(-d); base = h * h; }
  double f = (h <= 2.0) ? 1.0 : (h <= 4.0) ? 1.5 : (h <= 8.0) ? 2.0 : (h <= 16.0) ? 3.0 : 5.0;
  return base * f;
}

__global__ __launch_bounds__(256) void penalty_k(const u32* __restrict__ perm, const uint4* __restrict__ addr3,
                                                 double* __restrict__ partials) {
  int b = blockIdx.x >> 6; int blk = blockIdx.x & 63;
  int t = threadIdx.x, lane = t & 63;
  const u32* pm = perm + (size_t)b * NOPS_;
  const uint4* a3 = addr3 + (size_t)b * HW_;
  double intra = 0.0, inter = 0.0;
#pragma unroll
  for (int s = 0; s < 4; ++s) {
    int tg = blk * 1024 + s * 256 + t;
    u32 p = pm[tg];
    uint4 g = a3[p];
    float a0 = (float)g.x, a1 = (float)g.y, a2 = (float)g.z;
    intra += stagedp(a1 - a0) + stagedp(a2 - a1);
    float a2p = __shfl_up(a2, 1, 64);
    if (lane == 0 && tg > 0) {
      u32 pp = pm[tg - 1];
      a2p = (float)a3[pp].z;
    }
    if (tg > 0) inter += stagedp(a0 - a2p);
  }
#pragma unroll
  for (int m = 1; m < 64; m <<= 1) {
    intra += __shfl_xor(intra, m, 64);
    inter += __shfl_xor(inter, m, 64);
  }
  __shared__ double red[4][2];
  int wid = t >> 6;
  if (lane == 0) { red[wid][0] = inter; red[wid][1] = intra; }
  __syncthreads();
  if (t == 0) {
    double i0 = red[0][0] + red[1][0] + red[2][0] + red[3][0];
    double i1 = red[0][1] + red[1][1] + red[2][1] + red[3][1];
    partials[((size_t)b * 64 + blk) * 2 + 0] = i0;
    partials[((size_t)b * 64 + blk) * 2 + 1] = i1;
  }
}

__global__ void fin_k(const double* __restrict__ partials, float* __restrict__ out) {
  int t = threadIdx.x;
  if (t < 16) {
    int which = t >> 3, b = t & 7;
    double s = 0.0;
    for (int k = 0; k < 64; ++k) s += partials[((size_t)b * 64 + k) * 2 + which];
    out[which * 8 + b] = (float)s;
  }
}

// ---------------- host ----------------
extern "C" void kernel_launch(void* const* d_in, const int* in_sizes, int n_in,
                              void* d_out, int out_size, void* d_ws, size_t ws_size,
                              hipStream_t stream) {
  const float* logits = (const float*)d_in[0];
  const float* w1 = (const float*)d_in[1];
  const float* b1 = (const float*)d_in[2];
  const float* w2 = (const float*)d_in[3];
  const float* b2 = (const float*)d_in[4];
  const float* pw = (const float*)d_in[5];
  const float* pb = (const float*)d_in[6];
  float* out = (float*)d_out;

  char* ws = (char*)d_ws;
  size_t o = 0;
  auto take = [&](size_t bytes) { char* p = ws + o; o += (bytes + 255) & ~(size_t)255; return p; };
  u64* kv1A = (u64*)take((size_t)BN * N1 * 8);
  u64* kv1B = (u64*)take((size_t)BN * N1 * 8);
  u64* kv2A = (u64*)take((size_t)BN * NOPS_ * 8);
  u64* kv2B = (u64*)take((size_t)BN * NOPS_ * 8);
  u32* hist = (u32*)take((size_t)256 * NB1 * BN * 4);
  u32* dBase = (u32*)take((size_t)BN * 256 * 4);
  u32* addr = (u32*)take((size_t)BN * N1 * 4);
  float* mem = (float*)take((size_t)BN * N1 * 8 * 4);
  float* gPartial = (float*)take((size_t)BN * 4 * 64 * 64 * 4);
  float* flatS = (float*)take((size_t)BN * 256 * 4);
  u32* perm = (u32*)take((size_t)BN * NOPS_ * 4);
  double* partials = (double*)take((size_t)BN * 64 * 2 * 8);
  uint4* addr3 = (uint4*)kv1A;   // alias: kv1A dead after sort-1 pass 2

  // sort 1: stable argsort of mem_logits (keys bit-identical to reference)
  bk_kernel<<<BN * N1 / 256, 256, 0, stream>>>(logits, kv1A, N1);
  u64* src = kv1A; u64* dst = kv1B;
  for (int p = 0; p < 4; ++p) {
    rs_hist<<<BN * NB1, 256, 0, stream>>>(src, hist, N1, NB1, p * 8);
    rs_scan<<<BN, 1024, 0, stream>>>(hist, dBase, NB1);
    if (p < 3) {
      rs_scatter<false><<<BN * NB1, 256, 0, stream>>>(src, dst, nullptr, hist, dBase, N1, NB1, p * 8);
      u64* tmp = src; src = dst; dst = tmp;
    } else {
      rs_scatter<true><<<BN * NB1, 256, 0, stream>>>(src, nullptr, addr, hist, dBase, N1, NB1, p * 8);
    }
  }

  // conv1 + permutation scatter into mem [B][N1][8]
  conv1_scatter<<<BN * 3 * 64, 256, 0, stream>>>(addr, w1, b1, mem);

  // interleaved addr table (aliases kv1A — dead now)
  addr3_k<<<BN * HW_ / 256, 256, 0, stream>>>(addr, addr3);

  // conv2 + adaptive pool (two-stage deterministic reduction)
  c2p1<<<BN * 256, 256, 0, stream>>>(mem, w2, b2, gPartial);
  c2p2<<<BN, 256, 0, stream>>>(gPartial, flatS);

  // projection GEMV (+ sort-2 key build)
  proj_k<<<NOPS_ / 16, 256, 0, stream>>>(flatS, pw, pb, kv2A);

  // sort 2: stable argsort of op_logits
  src = kv2A; dst = kv2B;
  for (int p = 0; p < 4; ++p) {
    rs_hist<<<BN * NB2, 256, 0, stream>>>(src, hist, NOPS_, NB2, p * 8);
    rs_scan<<<BN, 1024, 0, stream>>>(hist, dBase, NB2);
    if (p < 3) {
      rs_scatter<false><<<BN * NB2, 256, 0, stream>>>(src, dst, nullptr, hist, dBase, NOPS_, NB2, p * 8);
      u64* tmp = src; src = dst; dst = tmp;
    } else {
      rs_scatter<true><<<BN * NB2, 256, 0, stream>>>(src, nullptr, perm, hist, dBase, NOPS_, NB2, p * 8);
    }
  }

  // staged penalties
  penalty_k<<<BN * 64, 256, 0, stream>>>(perm, addr3, partials);
  fin_k<<<1, 64, 0, stream>>>(partials, out);
}

// Round 4
// 298.203 us; speedup vs baseline: 3.9560x; 1.4859x over previous
//
#include <hip/hip_runtime.h>
#include <stdint.h>

typedef unsigned int u32;
typedef unsigned long long u64;

#define BN 8
#define HW_ 65536
#define N1 196608
#define NOPS_ 65536
#define NROWS_ 24576
#define NB1 192
#define NB2 64

// ---------------- sort key transform ----------------
__device__ __forceinline__ u32 fkey(float x) {
  u32 u = __float_as_uint(x);
  return u ^ ((u & 0x80000000u) ? 0xFFFFFFFFu : 0x80000000u);
}

// ---------------- radix pass: histogram (1024 items/block) + global digit totals ----------------
template <bool FIRST>
__global__ __launch_bounds__(256) void rs_hist(const u64* __restrict__ kv, const float* __restrict__ xf,
                                               u32* __restrict__ hist, u32* __restrict__ gTot,
                                               int n, int nblk, int shift) {
  __shared__ u32 h[256];
  int t = threadIdx.x;
  int b = blockIdx.x / nblk, blk = blockIdx.x % nblk;
  h[t] = 0;
  __syncthreads();
  if (FIRST) {
    const float* xp = xf + (size_t)b * n + (size_t)blk * 1024;
#pragma unroll
    for (int j = 0; j < 4; ++j) {
      u32 d = fkey(xp[j * 256 + t]) & 255u;
      atomicAdd(&h[d], 1u);
    }
  } else {
    const u64* kp = kv + (size_t)b * n + (size_t)blk * 1024;
#pragma unroll
    for (int j = 0; j < 4; ++j) {
      u32 d = (u32)(kp[j * 256 + t] >> (32 + shift)) & 255u;
      atomicAdd(&h[d], 1u);
    }
  }
  __syncthreads();
  hist[((size_t)b * 256 + t) * nblk + blk] = h[t];
  atomicAdd(&gTot[b * 256 + t], h[t]);   // integer atomics: order-independent -> deterministic
}

// ---------------- wave-parallel scan helpers ----------------
__device__ __forceinline__ u32 wscan_incl(u32 x, int lane) {
#pragma unroll
  for (int off = 1; off < 64; off <<= 1) {
    u32 y = __shfl_up(x, off, 64);
    if (lane >= off) x += y;
  }
  return x;
}

// per-digit block-offset scan, with digit base folded in. grid = BN*64, 256 thr (wave = one digit)
__global__ __launch_bounds__(256) void rs_scanB(u32* __restrict__ hist, const u32* __restrict__ gTot, int nblk) {
  int t = threadIdx.x, w = t >> 6, lane = t & 63;
  int b = blockIdx.x >> 6, dgrp = blockIdx.x & 63;
  int d = dgrp * 4 + w;
  const u32* gt = gTot + b * 256;
  u32 base = 0, run = 0;
  int dc = d >> 6, dl = d & 63;
#pragma unroll
  for (int c = 0; c < 4; ++c) {
    u32 v = gt[c * 64 + lane];
    u32 incl = wscan_incl(v, lane);
    if (c == dc) base = run + __shfl(incl - v, dl, 64);
    run += __shfl(incl, 63, 64);
  }
  u32* p = hist + ((size_t)b * 256 + d) * nblk;
  u32 acc = base;
  for (int c = 0; c < nblk; c += 64) {
    u32 v = p[c + lane];
    u32 incl = wscan_incl(v, lane);
    p[c + lane] = acc + incl - v;
    acc += __shfl(incl, 63, 64);
  }
}

// ---------------- radix pass: stable scatter v3 (3 barriers) ----------------
template <bool FIRST, bool FINAL>
__global__ __launch_bounds__(256) void rs_scatter(const u64* __restrict__ kvIn, const float* __restrict__ xf,
                                                  u64* __restrict__ out64, u32* __restrict__ out32,
                                                  const u32* __restrict__ hist, int n, int nblk, int shift) {
  __shared__ u32 sBase[256];
  __shared__ u32 cnt[16][256];   // [strip*4+wave][digit]
  int t = threadIdx.x, lane = t & 63, wid = t >> 6;
  int b = blockIdx.x / nblk, blk = blockIdx.x % nblk;
  u64 kvr[4]; u32 dg[4];
  if (FIRST) {
    const float* xp = xf + (size_t)b * n + (size_t)blk * 1024;
#pragma unroll
    for (int j = 0; j < 4; ++j) {
      u32 k = fkey(xp[j * 256 + t]);
      kvr[j] = ((u64)k << 32) | (u32)(blk * 1024 + j * 256 + t);
      dg[j] = k & 255u;
    }
  } else {
    const u64* kp = kvIn + (size_t)b * n + (size_t)blk * 1024;
#pragma unroll
    for (int j = 0; j < 4; ++j) {
      kvr[j] = kp[j * 256 + t];
      dg[j] = (u32)(kvr[j] >> (32 + shift)) & 255u;
    }
  }
  sBase[t] = hist[((size_t)b * 256 + t) * nblk + blk];
#pragma unroll
  for (int r = 0; r < 16; ++r) cnt[r][t] = 0;
  __syncthreads();
  u64 lmask = (1ull << lane) - 1ull;
  u32 rw[4];
#pragma unroll
  for (int j = 0; j < 4; ++j) {
    u32 d = dg[j];
    u64 peers = ~0ull;
#pragma unroll
    for (int bit = 0; bit < 8; ++bit) {
      u64 bal = __ballot((d >> bit) & 1);
      peers &= ((d >> bit) & 1) ? bal : ~bal;
    }
    u64 lower = peers & lmask;
    rw[j] = (u32)__popcll(lower);
    if (lower == 0) cnt[j * 4 + wid][d] = (u32)__popcll(peers);
  }
  __syncthreads();
  // thread t owns digit t: in-place serial prefix in item order (strip, wave) -> stability
  u32 run = sBase[t];
#pragma unroll
  for (int r = 0; r < 16; ++r) { u32 c = cnt[r][t]; cnt[r][t] = run; run += c; }
  __syncthreads();
#pragma unroll
  for (int j = 0; j < 4; ++j) {
    u32 pos = cnt[j * 4 + wid][dg[j]] + rw[j];
    if (FINAL) out32[(size_t)b * n + pos] = (u32)kvr[j];
    else out64[(size_t)b * n + pos] = kvr[j];
  }
}

// ---------------- conv1 (grouped 1->8, 3x3 SAME) fused with permutation scatter ----------------
__global__ __launch_bounds__(256) void conv1_scatter(const u32* __restrict__ addr, const float* __restrict__ w1,
                                                     const float* __restrict__ b1, float* __restrict__ mem) {
  __shared__ float ax[34][34];
  __shared__ float ws[8][9];
  __shared__ float bs[8];
  int t = threadIdx.x;
  int blk = blockIdx.x;
  int tile = blk & 63; int bk2 = blk >> 6; int k = bk2 % 3; int b = bk2 / 3;
  int ty = tile >> 3, tx = tile & 7;
  if (t < 72) ws[t / 9][t % 9] = w1[k * 72 + t];
  if (t >= 128 && t < 136) bs[t - 128] = b1[k * 8 + (t - 128)];
  const u32* ap = addr + (size_t)b * N1 + (size_t)k * HW_;
  for (int idx = t; idx < 34 * 34; idx += 256) {
    int y = idx / 34, x = idx % 34;
    int h = ty * 32 + y - 1, w = tx * 32 + x - 1;
    float v = 0.f;
    if (h >= 0 && h < 256 && w >= 0 && w < 256) v = (float)ap[h * 256 + w];
    ax[y][x] = v;
  }
  __syncthreads();
  float* mb = mem + (size_t)b * N1 * 8;
#pragma unroll
  for (int s = 0; s < 4; ++s) {
    int p = t + s * 256;
    int y = p >> 5, x = p & 31;
    float f[8];
#pragma unroll
    for (int c = 0; c < 8; ++c) f[c] = bs[c];
#pragma unroll
    for (int dy = 0; dy < 3; ++dy)
#pragma unroll
      for (int dx = 0; dx < 3; ++dx) {
        float v = ax[y + dy][x + dx];
#pragma unroll
        for (int c = 0; c < 8; ++c) f[c] = fmaf(ws[c][dy * 3 + dx], v, f[c]);
      }
    u32 a = (u32)ax[y + 1][x + 1];
    float4* dst = reinterpret_cast<float4*>(mb + (size_t)a * 8);
    float4 lo = make_float4(fmaxf(f[0], 0.f), fmaxf(f[1], 0.f), fmaxf(f[2], 0.f), fmaxf(f[3], 0.f));
    float4 hi = make_float4(fmaxf(f[4], 0.f), fmaxf(f[5], 0.f), fmaxf(f[6], 0.f), fmaxf(f[7], 0.f));
    dst[0] = lo; dst[1] = hi;
  }
}

// ---------------- conv2 + pool (R2 version: 56 us, VGPR 56) ----------------
__global__ __launch_bounds__(256, 3) void c2p1(const float* __restrict__ mem, const float* __restrict__ w2,
                                               const float* __restrict__ b2, float* __restrict__ gPartial) {
  __shared__ float tile[98 * 68];
  __shared__ float w2s[1152];
  __shared__ float b2s[16];
  __shared__ float red[16][64];   // [rowgrp][lb*16+co]
  int blk = blockIdx.x; int sub = blk & 255; int b = blk >> 8;
  int r0 = sub * 96;
  int t = threadIdx.x;
  for (int idx = t; idx < 1152; idx += 256) w2s[idx] = w2[idx];
  if (t < 16) b2s[t] = b2[t];
  const float* mb = mem + (size_t)b * (N1 * 8);
  for (int q = t; q < 98 * 16; q += 256) {
    int ti = q >> 4, qw = q & 15;
    int r = r0 - 1 + ti;
    float4 v = make_float4(0.f, 0.f, 0.f, 0.f);
    if (r >= 0 && r < NROWS_) v = *reinterpret_cast<const float4*>(mb + (size_t)r * 64 + qw * 4);
    *reinterpret_cast<float4*>(&tile[ti * 68 + qw * 4]) = v;
  }
  __syncthreads();
  int co = t & 15, rowgrp = t >> 4;
  float wreg[3][3][8];
#pragma unroll
  for (int ci = 0; ci < 8; ++ci)
#pragma unroll
    for (int kr = 0; kr < 3; ++kr)
#pragma unroll
      for (int kc = 0; kc < 3; ++kc)
        wreg[kr][kc][ci] = w2s[(co * 8 + ci) * 9 + kr * 3 + kc];
  float bias = b2s[co];
  float pool[4] = {0.f, 0.f, 0.f, 0.f};
#pragma unroll 1
  for (int i = 0; i < 3; ++i) {
    int lr0 = rowgrp * 2 + 32 * i;     // local output row pair (lr0, lr0+1)
    float s0[8], s1[8];
#pragma unroll
    for (int l = 0; l < 8; ++l) { s0[l] = 0.f; s1[l] = 0.f; }
#pragma unroll
    for (int j = 0; j < 4; ++j) {      // input tile rows lr0 .. lr0+3
      const float* trow = &tile[(lr0 + j) * 68];
#pragma unroll
      for (int li = 0; li < 8; ++li) { // input lane
        float4 aa = *reinterpret_cast<const float4*>(trow + li * 8);
        float4 bb = *reinterpret_cast<const float4*>(trow + li * 8 + 4);
        float in[8] = {aa.x, aa.y, aa.z, aa.w, bb.x, bb.y, bb.z, bb.w};
#pragma unroll
        for (int ci = 0; ci < 8; ++ci) {
          float v = in[ci];
          if (j < 3) {                 // output row lr0, kr = j
            if (li >= 1) s0[li - 1] = fmaf(v, wreg[j][2][ci], s0[li - 1]);
            s0[li] = fmaf(v, wreg[j][1][ci], s0[li]);
            if (li < 7) s0[li + 1] = fmaf(v, wreg[j][0][ci], s0[li + 1]);
          }
          if (j >= 1) {                // output row lr0+1, kr = j-1
            if (li >= 1) s1[li - 1] = fmaf(v, wreg[j - 1][2][ci], s1[li - 1]);
            s1[li] = fmaf(v, wreg[j - 1][1][ci], s1[li]);
            if (li < 7) s1[li + 1] = fmaf(v, wreg[j - 1][0][ci], s1[li + 1]);
          }
        }
      }
    }
#pragma unroll
    for (int l = 0; l < 8; ++l)
      pool[l >> 1] += fmaxf(s0[l] + bias, 0.f) + fmaxf(s1[l] + bias, 0.f);
  }
#pragma unroll
  for (int lb = 0; lb < 4; ++lb) red[rowgrp][lb * 16 + co] = pool[lb];
  __syncthreads();
  if (t < 64) {
    float s = 0.f;
#pragma unroll
    for (int rg = 0; rg < 16; ++rg) s += red[rg][t];
    int rb = sub >> 6, subW = sub & 63;
    gPartial[(((size_t)(b * 4 + rb) * 64 + subW) * 64) + t] = s;
  }
}

// deterministic stage-2 reduce -> flat [B][256] (order ch*16 + rb*4 + lb)
__global__ void c2p2(const float* __restrict__ gPartial, float* __restrict__ flatS) {
  int b = blockIdx.x; int t = threadIdx.x;
  int ch = t >> 4; int rb = (t >> 2) & 3; int lb = t & 3;
  float s = 0.f;
  for (int sub = 0; sub < 64; ++sub)
    s += gPartial[(((size_t)(b * 4 + rb) * 64 + sub) * 64) + lb * 16 + ch];
  flatS[b * 256 + t] = s * (1.0f / 12288.0f);
}

// ---------------- projection GEMV fused with sort-2 key build ----------------
__global__ __launch_bounds__(256) void proj_k(const float* __restrict__ flatS, const float* __restrict__ pw,
                                              const float* __restrict__ pb, u64* __restrict__ kv2) {
  __shared__ float fs[8][256];
  int t = threadIdx.x;
  for (int i = t; i < 2048; i += 256) fs[i >> 8][i & 255] = flatS[i];
  __syncthreads();
  int q = t & 15; int og = t >> 4;
  int o = blockIdx.x * 16 + og;
  float acc[8];
#pragma unroll
  for (int b = 0; b < 8; ++b) acc[b] = 0.f;
  const float* wr = pw + (size_t)o * 256;
#pragma unroll
  for (int j = 0; j < 16; ++j) {
    float w = wr[q + 16 * j];
#pragma unroll
    for (int b = 0; b < 8; ++b) acc[b] = fmaf(fs[b][q + 16 * j], w, acc[b]);
  }
#pragma unroll
  for (int m = 1; m < 16; m <<= 1)
#pragma unroll
    for (int b = 0; b < 8; ++b) acc[b] += __shfl_xor(acc[b], m, 64);
  if (q == 0) {
    float bias = pb[o];
#pragma unroll
    for (int b = 0; b < 8; ++b) {
      u32 k = fkey(acc[b] + bias);
      kv2[(size_t)b * NOPS_ + o] = ((u64)k << 32) | (u32)o;
    }
  }
}

// ---------------- interleaved addr table for penalty gathers ----------------
__global__ void addr3_k(const u32* __restrict__ addr, uint4* __restrict__ addr3) {
  int i = blockIdx.x * 256 + threadIdx.x;
  int b = i >> 16, p = i & (HW_ - 1);
  const u32* ad = addr + (size_t)b * N1;
  addr3[(size_t)b * HW_ + p] = make_uint4(ad[p], ad[HW_ + p], ad[2 * HW_ + p], 0u);
}

// ---------------- staged penalty (integer-exact, double accumulation) ----------------
__device__ __forceinline__ double stagedp(float d) {
  double h, base;
  if (d >= 0.f) { h = (double)d; base = h; }
  else { h = (double)(-d); base = h * h; }
  double f = (h <= 2.0) ? 1.0 : (h <= 4.0) ? 1.5 : (h <= 8.0) ? 2.0 : (h <= 16.0) ? 3.0 : 5.0;
  return base * f;
}

__global__ __launch_bounds__(256) void penalty_k(const u32* __restrict__ perm, const uint4* __restrict__ addr3,
                                                 double* __restrict__ partials) {
  int b = blockIdx.x >> 6; int blk = blockIdx.x & 63;
  int t = threadIdx.x, lane = t & 63;
  const u32* pm = perm + (size_t)b * NOPS_;
  const uint4* a3 = addr3 + (size_t)b * HW_;
  double intra = 0.0, inter = 0.0;
#pragma unroll
  for (int s = 0; s < 4; ++s) {
    int tg = blk * 1024 + s * 256 + t;
    u32 p = pm[tg];
    uint4 g = a3[p];
    float a0 = (float)g.x, a1 = (float)g.y, a2 = (float)g.z;
    intra += stagedp(a1 - a0) + stagedp(a2 - a1);
    float a2p = __shfl_up(a2, 1, 64);
    if (lane == 0 && tg > 0) {
      u32 pp = pm[tg - 1];
      a2p = (float)a3[pp].z;
    }
    if (tg > 0) inter += stagedp(a0 - a2p);
  }
#pragma unroll
  for (int m = 1; m < 64; m <<= 1) {
    intra += __shfl_xor(intra, m, 64);
    inter += __shfl_xor(inter, m, 64);
  }
  __shared__ double red[4][2];
  int wid = t >> 6;
  if (lane == 0) { red[wid][0] = inter; red[wid][1] = intra; }
  __syncthreads();
  if (t == 0) {
    double i0 = red[0][0] + red[1][0] + red[2][0] + red[3][0];
    double i1 = red[0][1] + red[1][1] + red[2][1] + red[3][1];
    partials[((size_t)b * 64 + blk) * 2 + 0] = i0;
    partials[((size_t)b * 64 + blk) * 2 + 1] = i1;
  }
}

__global__ void fin_k(const double* __restrict__ partials, float* __restrict__ out) {
  int t = threadIdx.x;
  if (t < 16) {
    int which = t >> 3, b = t & 7;
    double s = 0.0;
    for (int k = 0; k < 64; ++k) s += partials[((size_t)b * 64 + k) * 2 + which];
    out[which * 8 + b] = (float)s;
  }
}

// ---------------- host ----------------
extern "C" void kernel_launch(void* const* d_in, const int* in_sizes, int n_in,
                              void* d_out, int out_size, void* d_ws, size_t ws_size,
                              hipStream_t stream) {
  const float* logits = (const float*)d_in[0];
  const float* w1 = (const float*)d_in[1];
  const float* b1 = (const float*)d_in[2];
  const float* w2 = (const float*)d_in[3];
  const float* b2 = (const float*)d_in[4];
  const float* pw = (const float*)d_in[5];
  const float* pb = (const float*)d_in[6];
  float* out = (float*)d_out;

  char* ws = (char*)d_ws;
  size_t o = 0;
  auto take = [&](size_t bytes) { char* p = ws + o; o += (bytes + 255) & ~(size_t)255; return p; };
  u64* kv1A = (u64*)take((size_t)BN * N1 * 8);
  u64* kv1B = (u64*)take((size_t)BN * N1 * 8);
  u64* kv2A = (u64*)take((size_t)BN * NOPS_ * 8);
  u64* kv2B = (u64*)take((size_t)BN * NOPS_ * 8);
  u32* hist = (u32*)take((size_t)256 * NB1 * BN * 4);
  u32* gTotAll = (u32*)take((size_t)8 * BN * 256 * 4);
  u32* addr = (u32*)take((size_t)BN * N1 * 4);
  float* mem = (float*)take((size_t)BN * N1 * 8 * 4);
  float* gPartial = (float*)take((size_t)BN * 4 * 64 * 64 * 4);
  float* flatS = (float*)take((size_t)BN * 256 * 4);
  u32* perm = (u32*)take((size_t)BN * NOPS_ * 4);
  double* partials = (double*)take((size_t)BN * 64 * 2 * 8);
  uint4* addr3 = (uint4*)kv1A;   // alias: kv1A dead after sort-1

  hipMemsetAsync(gTotAll, 0, (size_t)8 * BN * 256 * 4, stream);

  // sort 1: stable argsort of mem_logits (pass 0 builds keys from logits on the fly)
  {
    u32* gT = gTotAll;
    rs_hist<true><<<BN * NB1, 256, 0, stream>>>(nullptr, logits, hist, gT, N1, NB1, 0);
    rs_scanB<<<BN * 64, 256, 0, stream>>>(hist, gT, NB1);
    rs_scatter<true, false><<<BN * NB1, 256, 0, stream>>>(nullptr, logits, kv1B, nullptr, hist, N1, NB1, 0);
  }
  u64* src = kv1B; u64* dst = kv1A;
  for (int p = 1; p < 4; ++p) {
    u32* gT = gTotAll + (size_t)p * BN * 256;
    rs_hist<false><<<BN * NB1, 256, 0, stream>>>(src, nullptr, hist, gT, N1, NB1, p * 8);
    rs_scanB<<<BN * 64, 256, 0, stream>>>(hist, gT, NB1);
    if (p < 3) {
      rs_scatter<false, false><<<BN * NB1, 256, 0, stream>>>(src, nullptr, dst, nullptr, hist, N1, NB1, p * 8);
      u64* tmp = src; src = dst; dst = tmp;
    } else {
      rs_scatter<false, true><<<BN * NB1, 256, 0, stream>>>(src, nullptr, nullptr, addr, hist, N1, NB1, p * 8);
    }
  }

  // conv1 + permutation scatter into mem [B][N1][8]
  conv1_scatter<<<BN * 3 * 64, 256, 0, stream>>>(addr, w1, b1, mem);

  // interleaved addr table (aliases kv1A — dead now)
  addr3_k<<<BN * HW_ / 256, 256, 0, stream>>>(addr, addr3);

  // conv2 + adaptive pool (two-stage deterministic reduction)
  c2p1<<<BN * 256, 256, 0, stream>>>(mem, w2, b2, gPartial);
  c2p2<<<BN, 256, 0, stream>>>(gPartial, flatS);

  // projection GEMV (+ sort-2 key build)
  proj_k<<<NOPS_ / 16, 256, 0, stream>>>(flatS, pw, pb, kv2A);

  // sort 2: stable argsort of op_logits
  src = kv2A; dst = kv2B;
  for (int p = 0; p < 4; ++p) {
    u32* gT = gTotAll + (size_t)(4 + p) * BN * 256;
    rs_hist<false><<<BN * NB2, 256, 0, stream>>>(src, nullptr, hist, gT, NOPS_, NB2, p * 8);
    rs_scanB<<<BN * 64, 256, 0, stream>>>(hist, gT, NB2);
    if (p < 3) {
      rs_scatter<false, false><<<BN * NB2, 256, 0, stream>>>(src, nullptr, dst, nullptr, hist, NOPS_, NB2, p * 8);
      u64* tmp = src; src = dst; dst = tmp;
    } else {
      rs_scatter<false, true><<<BN * NB2, 256, 0, stream>>>(src, nullptr, nullptr, perm, hist, NOPS_, NB2, p * 8);
    }
  }

  // staged penalties
  penalty_k<<<BN * 64, 256, 0, stream>>>(perm, addr3, partials);
  fin_k<<<1, 64, 0, stream>>>(partials, out);
}

// Round 6
// 294.479 us; speedup vs baseline: 4.0060x; 1.0126x over previous
//
#include <hip/hip_runtime.h>
#include <stdint.h>

typedef unsigned int u32;
typedef unsigned long long u64;

#define BN 8
#define HW_ 65536
#define N1 196608
#define NOPS_ 65536
#define NROWS_ 24576
#define NB1 192
#define NB2 64

// ---------------- sort key transform ----------------
__device__ __forceinline__ u32 fkey(float x) {
  u32 u = __float_as_uint(x);
  return u ^ ((u & 0x80000000u) ? 0xFFFFFFFFu : 0x80000000u);
}

// ---------------- radix pass: histogram (1024 items/block) + global digit totals ----------------
template <bool FIRST>
__global__ __launch_bounds__(256) void rs_hist(const u64* __restrict__ kv, const float* __restrict__ xf,
                                               u32* __restrict__ hist, u32* __restrict__ gTot,
                                               int n, int nblk, int shift) {
  __shared__ u32 h[256];
  int t = threadIdx.x;
  int b = blockIdx.x / nblk, blk = blockIdx.x % nblk;
  h[t] = 0;
  __syncthreads();
  if (FIRST) {
    const float* xp = xf + (size_t)b * n + (size_t)blk * 1024;
#pragma unroll
    for (int j = 0; j < 4; ++j) {
      u32 d = fkey(xp[j * 256 + t]) & 255u;
      atomicAdd(&h[d], 1u);
    }
  } else {
    const u64* kp = kv + (size_t)b * n + (size_t)blk * 1024;
#pragma unroll
    for (int j = 0; j < 4; ++j) {
      u32 d = (u32)(kp[j * 256 + t] >> (32 + shift)) & 255u;
      atomicAdd(&h[d], 1u);
    }
  }
  __syncthreads();
  hist[((size_t)b * 256 + t) * nblk + blk] = h[t];
  atomicAdd(&gTot[b * 256 + t], h[t]);   // integer atomics: order-independent -> deterministic
}

// ---------------- wave-parallel scan helpers ----------------
__device__ __forceinline__ u32 wscan_incl(u32 x, int lane) {
#pragma unroll
  for (int off = 1; off < 64; off <<= 1) {
    u32 y = __shfl_up(x, off, 64);
    if (lane >= off) x += y;
  }
  return x;
}

// per-digit block-offset scan, with digit base folded in. grid = BN*64, 256 thr (wave = one digit)
__global__ __launch_bounds__(256) void rs_scanB(u32* __restrict__ hist, const u32* __restrict__ gTot, int nblk) {
  int t = threadIdx.x, w = t >> 6, lane = t & 63;
  int b = blockIdx.x >> 6, dgrp = blockIdx.x & 63;
  int d = dgrp * 4 + w;
  const u32* gt = gTot + b * 256;
  u32 base = 0, run = 0;
  int dc = d >> 6, dl = d & 63;
#pragma unroll
  for (int c = 0; c < 4; ++c) {
    u32 v = gt[c * 64 + lane];
    u32 incl = wscan_incl(v, lane);
    if (c == dc) base = run + __shfl(incl - v, dl, 64);
    run += __shfl(incl, 63, 64);
  }
  u32* p = hist + ((size_t)b * 256 + d) * nblk;
  u32 acc = base;
  for (int c = 0; c < nblk; c += 64) {
    u32 v = p[c + lane];
    u32 incl = wscan_incl(v, lane);
    p[c + lane] = acc + incl - v;
    acc += __shfl(incl, 63, 64);
  }
}

// ---------------- radix pass: stable scatter v3 (3 barriers) ----------------
template <bool FIRST, bool FINAL>
__global__ __launch_bounds__(256) void rs_scatter(const u64* __restrict__ kvIn, const float* __restrict__ xf,
                                                  u64* __restrict__ out64, u32* __restrict__ out32,
                                                  const u32* __restrict__ hist, int n, int nblk, int shift) {
  __shared__ u32 sBase[256];
  __shared__ u32 cnt[16][256];   // [strip*4+wave][digit]
  int t = threadIdx.x, lane = t & 63, wid = t >> 6;
  int b = blockIdx.x / nblk, blk = blockIdx.x % nblk;
  u64 kvr[4]; u32 dg[4];
  if (FIRST) {
    const float* xp = xf + (size_t)b * n + (size_t)blk * 1024;
#pragma unroll
    for (int j = 0; j < 4; ++j) {
      u32 k = fkey(xp[j * 256 + t]);
      kvr[j] = ((u64)k << 32) | (u32)(blk * 1024 + j * 256 + t);
      dg[j] = k & 255u;
    }
  } else {
    const u64* kp = kvIn + (size_t)b * n + (size_t)blk * 1024;
#pragma unroll
    for (int j = 0; j < 4; ++j) {
      kvr[j] = kp[j * 256 + t];
      dg[j] = (u32)(kvr[j] >> (32 + shift)) & 255u;
    }
  }
  sBase[t] = hist[((size_t)b * 256 + t) * nblk + blk];
#pragma unroll
  for (int r = 0; r < 16; ++r) cnt[r][t] = 0;
  __syncthreads();
  u64 lmask = (1ull << lane) - 1ull;
  u32 rw[4];
#pragma unroll
  for (int j = 0; j < 4; ++j) {
    u32 d = dg[j];
    u64 peers = ~0ull;
#pragma unroll
    for (int bit = 0; bit < 8; ++bit) {
      u64 bal = __ballot((d >> bit) & 1);
      peers &= ((d >> bit) & 1) ? bal : ~bal;
    }
    u64 lower = peers & lmask;
    rw[j] = (u32)__popcll(lower);
    if (lower == 0) cnt[j * 4 + wid][d] = (u32)__popcll(peers);
  }
  __syncthreads();
  // thread t owns digit t: in-place serial prefix in item order (strip, wave) -> stability
  u32 run = sBase[t];
#pragma unroll
  for (int r = 0; r < 16; ++r) { u32 c = cnt[r][t]; cnt[r][t] = run; run += c; }
  __syncthreads();
#pragma unroll
  for (int j = 0; j < 4; ++j) {
    u32 pos = cnt[j * 4 + wid][dg[j]] + rw[j];
    if (FINAL) out32[(size_t)b * n + pos] = (u32)kvr[j];
    else out64[(size_t)b * n + pos] = kvr[j];
  }
}

// ---------------- conv1 (grouped 1->8, 3x3 SAME) + permutation scatter + addr3 build (k==0) ----------------
__global__ __launch_bounds__(256) void conv1_scatter(const u32* __restrict__ addr, const float* __restrict__ w1,
                                                     const float* __restrict__ b1, float* __restrict__ mem,
                                                     uint4* __restrict__ addr3) {
  __shared__ float ax[34][34];
  __shared__ float ws[8][9];
  __shared__ float bs[8];
  int t = threadIdx.x;
  int blk = blockIdx.x;
  int tile = blk & 63; int bk2 = blk >> 6; int k = bk2 % 3; int b = bk2 / 3;
  int ty = tile >> 3, tx = tile & 7;
  if (t < 72) ws[t / 9][t % 9] = w1[k * 72 + t];
  if (t >= 128 && t < 136) bs[t - 128] = b1[k * 8 + (t - 128)];
  const u32* ap = addr + (size_t)b * N1 + (size_t)k * HW_;
  for (int idx = t; idx < 34 * 34; idx += 256) {
    int y = idx / 34, x = idx % 34;
    int h = ty * 32 + y - 1, w = tx * 32 + x - 1;
    float v = 0.f;
    if (h >= 0 && h < 256 && w >= 0 && w < 256) v = (float)ap[h * 256 + w];
    ax[y][x] = v;
  }
  __syncthreads();
  float* mb = mem + (size_t)b * N1 * 8;
  const u32* adb = addr + (size_t)b * N1;
  uint4* a3b = addr3 + (size_t)b * HW_;
#pragma unroll
  for (int s = 0; s < 4; ++s) {
    int p = t + s * 256;
    int y = p >> 5, x = p & 31;
    float f[8];
#pragma unroll
    for (int c = 0; c < 8; ++c) f[c] = bs[c];
#pragma unroll
    for (int dy = 0; dy < 3; ++dy)
#pragma unroll
      for (int dx = 0; dx < 3; ++dx) {
        float v = ax[y + dy][x + dx];
#pragma unroll
        for (int c = 0; c < 8; ++c) f[c] = fmaf(ws[c][dy * 3 + dx], v, f[c]);
      }
    u32 a = (u32)ax[y + 1][x + 1];
    float4* dst = reinterpret_cast<float4*>(mb + (size_t)a * 8);
    float4 lo = make_float4(fmaxf(f[0], 0.f), fmaxf(f[1], 0.f), fmaxf(f[2], 0.f), fmaxf(f[3], 0.f));
    float4 hi = make_float4(fmaxf(f[4], 0.f), fmaxf(f[5], 0.f), fmaxf(f[6], 0.f), fmaxf(f[7], 0.f));
    dst[0] = lo; dst[1] = hi;
    if (k == 0) {    // block-uniform branch: build interleaved addr3 table
      int gp = (ty * 32 + y) * 256 + tx * 32 + x;
      a3b[gp] = make_uint4(a, adb[HW_ + gp], adb[2 * HW_ + gp], 0u);
    }
  }
}

// ---------------- conv2 + pool: direct float4-component FMAs (no in[] repack) ----------------
__global__ __launch_bounds__(256, 3) void c2p1(const float* __restrict__ mem, const float* __restrict__ w2,
                                               const float* __restrict__ b2, float* __restrict__ gPartial) {
  __shared__ float tile[98 * 68];
  __shared__ float w2s[1152];
  __shared__ float b2s[16];
  __shared__ float red[16][64];   // [rowgrp][lb*16+co]
  int blk = blockIdx.x; int sub = blk & 255; int b = blk >> 8;
  int r0 = sub * 96;
  int t = threadIdx.x;
  for (int idx = t; idx < 1152; idx += 256) w2s[idx] = w2[idx];
  if (t < 16) b2s[t] = b2[t];
  const float* mb = mem + (size_t)b * (N1 * 8);
  for (int q = t; q < 98 * 16; q += 256) {
    int ti = q >> 4, qw = q & 15;
    int r = r0 - 1 + ti;
    float4 v = make_float4(0.f, 0.f, 0.f, 0.f);
    if (r >= 0 && r < NROWS_) v = *reinterpret_cast<const float4*>(mb + (size_t)r * 64 + qw * 4);
    *reinterpret_cast<float4*>(&tile[ti * 68 + qw * 4]) = v;
  }
  __syncthreads();
  int co = t & 15, rowgrp = t >> 4;
  float wreg[3][3][8];
#pragma unroll
  for (int ci = 0; ci < 8; ++ci)
#pragma unroll
    for (int kr = 0; kr < 3; ++kr)
#pragma unroll
      for (int kc = 0; kc < 3; ++kc)
        wreg[kr][kc][ci] = w2s[(co * 8 + ci) * 9 + kr * 3 + kc];
  float bias = b2s[co];
  float pool[4] = {0.f, 0.f, 0.f, 0.f};
// identical accumulation order to R2/R4 (ci ascending; s0 then s1 per ci)
#define CSTEP(V, CI) do { \
    if (j < 3) { \
      if (li >= 1) s0[li - 1] = fmaf((V), wreg[j][2][CI], s0[li - 1]); \
      s0[li] = fmaf((V), wreg[j][1][CI], s0[li]); \
      if (li < 7) s0[li + 1] = fmaf((V), wreg[j][0][CI], s0[li + 1]); \
    } \
    if (j >= 1) { \
      if (li >= 1) s1[li - 1] = fmaf((V), wreg[j - 1][2][CI], s1[li - 1]); \
      s1[li] = fmaf((V), wreg[j - 1][1][CI], s1[li]); \
      if (li < 7) s1[li + 1] = fmaf((V), wreg[j - 1][0][CI], s1[li + 1]); \
    } \
  } while (0)
#pragma unroll 1
  for (int i = 0; i < 3; ++i) {
    int lr0 = rowgrp * 2 + 32 * i;     // local output row pair (lr0, lr0+1)
    float s0[8], s1[8];
#pragma unroll
    for (int l = 0; l < 8; ++l) { s0[l] = 0.f; s1[l] = 0.f; }
#pragma unroll
    for (int j = 0; j < 4; ++j) {      // input tile rows lr0 .. lr0+3
      const float* trow = &tile[(lr0 + j) * 68];
#pragma unroll
      for (int li = 0; li < 8; ++li) { // input lane
        float4 aa = *reinterpret_cast<const float4*>(trow + li * 8);
        float4 bb = *reinterpret_cast<const float4*>(trow + li * 8 + 4);
        CSTEP(aa.x, 0); CSTEP(aa.y, 1); CSTEP(aa.z, 2); CSTEP(aa.w, 3);
        CSTEP(bb.x, 4); CSTEP(bb.y, 5); CSTEP(bb.z, 6); CSTEP(bb.w, 7);
      }
    }
#pragma unroll
    for (int l = 0; l < 8; ++l)
      pool[l >> 1] += fmaxf(s0[l] + bias, 0.f) + fmaxf(s1[l] + bias, 0.f);
  }
#undef CSTEP
#pragma unroll
  for (int lb = 0; lb < 4; ++lb) red[rowgrp][lb * 16 + co] = pool[lb];
  __syncthreads();
  if (t < 64) {
    float s = 0.f;
#pragma unroll
    for (int rg = 0; rg < 16; ++rg) s += red[rg][t];
    int rb = sub >> 6, subW = sub & 63;
    gPartial[(((size_t)(b * 4 + rb) * 64 + subW) * 64) + t] = s;
  }
}

// deterministic stage-2 reduce -> flat [B][256] (order ch*16 + rb*4 + lb)
__global__ void c2p2(const float* __restrict__ gPartial, float* __restrict__ flatS) {
  int b = blockIdx.x; int t = threadIdx.x;
  int ch = t >> 4; int rb = (t >> 2) & 3; int lb = t & 3;
  float s = 0.f;
  for (int sub = 0; sub < 64; ++sub)
    s += gPartial[(((size_t)(b * 4 + rb) * 64 + sub) * 64) + lb * 16 + ch];
  flatS[b * 256 + t] = s * (1.0f / 12288.0f);
}

// ---------------- projection GEMV fused with sort-2 key build ----------------
__global__ __launch_bounds__(256) void proj_k(const float* __restrict__ flatS, const float* __restrict__ pw,
                                              const float* __restrict__ pb, u64* __restrict__ kv2) {
  __shared__ float fs[8][256];
  int t = threadIdx.x;
  for (int i = t; i < 2048; i += 256) fs[i >> 8][i & 255] = flatS[i];
  __syncthreads();
  int q = t & 15; int og = t >> 4;
  int o = blockIdx.x * 16 + og;
  float acc[8];
#pragma unroll
  for (int b = 0; b < 8; ++b) acc[b] = 0.f;
  const float* wr = pw + (size_t)o * 256;
#pragma unroll
  for (int j = 0; j < 16; ++j) {
    float w = wr[q + 16 * j];
#pragma unroll
    for (int b = 0; b < 8; ++b) acc[b] = fmaf(fs[b][q + 16 * j], w, acc[b]);
  }
#pragma unroll
  for (int m = 1; m < 16; m <<= 1)
#pragma unroll
    for (int b = 0; b < 8; ++b) acc[b] += __shfl_xor(acc[b], m, 64);
  if (q == 0) {
    float bias = pb[o];
#pragma unroll
    for (int b = 0; b < 8; ++b) {
      u32 k = fkey(acc[b] + bias);
      kv2[(size_t)b * NOPS_ + o] = ((u64)k << 32) | (u32)o;
    }
  }
}

// ---------------- staged penalty (integer-exact, double accumulation) + fused final reduce ----------------
__device__ __forceinline__ double stagedp(float d) {
  double h, base;
  if (d >= 0.f) { h = (double)d; base = h; }
  else { h = (double)(-d); base = h * h; }
  double f = (h <= 2.0) ? 1.0 : (h <= 4.0) ? 1.5 : (h <= 8.0) ? 2.0 : (h <= 16.0) ? 3.0 : 5.0;
  return base * f;
}

__global__ __launch_bounds__(256) void penalty_k(const u32* __restrict__ perm, const uint4* __restrict__ addr3,
                                                 double* __restrict__ partials, u32* __restrict__ ctr,
                                                 float* __restrict__ out) {
  int b = blockIdx.x >> 6; int blk = blockIdx.x & 63;
  int t = threadIdx.x, lane = t & 63;
  const u32* pm = perm + (size_t)b * NOPS_;
  const uint4* a3 = addr3 + (size_t)b * HW_;
  double intra = 0.0, inter = 0.0;
#pragma unroll
  for (int s = 0; s < 4; ++s) {
    int tg = blk * 1024 + s * 256 + t;
    u32 p = pm[tg];
    uint4 g = a3[p];
    float a0 = (float)g.x, a1 = (float)g.y, a2 = (float)g.z;
    intra += stagedp(a1 - a0) + stagedp(a2 - a1);
    float a2p = __shfl_up(a2, 1, 64);
    if (lane == 0 && tg > 0) {
      u32 pp = pm[tg - 1];
      a2p = (float)a3[pp].z;
    }
    if (tg > 0) inter += stagedp(a0 - a2p);
  }
#pragma unroll
  for (int m = 1; m < 64; m <<= 1) {
    intra += __shfl_xor(intra, m, 64);
    inter += __shfl_xor(inter, m, 64);
  }
  __shared__ double red[4][2];
  __shared__ u32 lastFlag;
  int wid = t >> 6;
  if (lane == 0) { red[wid][0] = inter; red[wid][1] = intra; }
  __syncthreads();
  if (t == 0) {
    double i0 = red[0][0] + red[1][0] + red[2][0] + red[3][0];
    double i1 = red[0][1] + red[1][1] + red[2][1] + red[3][1];
    partials[((size_t)b * 64 + blk) * 2 + 0] = i0;
    partials[((size_t)b * 64 + blk) * 2 + 1] = i1;
    __threadfence();                       // release: publish partials
    u32 done = atomicAdd(ctr, 1u);         // device-scope
    lastFlag = (done == (u32)(BN * 64 - 1));
  }
  __syncthreads();
  if (lastFlag) {                          // exactly one block; fixed summation order -> deterministic
    __threadfence();                       // acquire: see all partials
    if (t < 16) {
      int which = t >> 3, bb = t & 7;
      double s = 0.0;
      for (int k = 0; k < 64; ++k) s += partials[((size_t)bb * 64 + k) * 2 + which];
      out[which * 8 + bb] = (float)s;
    }
  }
}

// ---------------- host ----------------
extern "C" void kernel_launch(void* const* d_in, const int* in_sizes, int n_in,
                              void* d_out, int out_size, void* d_ws, size_t ws_size,
                              hipStream_t stream) {
  const float* logits = (const float*)d_in[0];
  const float* w1 = (const float*)d_in[1];
  const float* b1 = (const float*)d_in[2];
  const float* w2 = (const float*)d_in[3];
  const float* b2 = (const float*)d_in[4];
  const float* pw = (const float*)d_in[5];
  const float* pb = (const float*)d_in[6];
  float* out = (float*)d_out;

  char* ws = (char*)d_ws;
  size_t o = 0;
  auto take = [&](size_t bytes) { char* p = ws + o; o += (bytes + 255) & ~(size_t)255; return p; };
  u64* kv1A = (u64*)take((size_t)BN * N1 * 8);
  u64* kv1B = (u64*)take((size_t)BN * N1 * 8);
  u64* kv2A = (u64*)take((size_t)BN * NOPS_ * 8);
  u64* kv2B = (u64*)take((size_t)BN * NOPS_ * 8);
  u32* hist = (u32*)take((size_t)256 * NB1 * BN * 4);
  u32* gTotAll = (u32*)take(((size_t)8 * BN * 256 + 64) * 4);   // + ctr slot
  u32* addr = (u32*)take((size_t)BN * N1 * 4);
  float* mem = (float*)take((size_t)BN * N1 * 8 * 4);
  float* gPartial = (float*)take((size_t)BN * 4 * 64 * 64 * 4);
  float* flatS = (float*)take((size_t)BN * 256 * 4);
  u32* perm = (u32*)take((size_t)BN * NOPS_ * 4);
  double* partials = (double*)take((size_t)BN * 64 * 2 * 8);
  uint4* addr3 = (uint4*)kv1A;                  // alias: kv1A dead after sort-1 pass 2
  u32* ctr = gTotAll + (size_t)8 * BN * 256;    // zeroed by the memset below

  hipMemsetAsync(gTotAll, 0, ((size_t)8 * BN * 256 + 64) * 4, stream);

  // sort 1: stable argsort of mem_logits (pass 0 builds keys from logits on the fly)
  {
    u32* gT = gTotAll;
    rs_hist<true><<<BN * NB1, 256, 0, stream>>>(nullptr, logits, hist, gT, N1, NB1, 0);
    rs_scanB<<<BN * 64, 256, 0, stream>>>(hist, gT, NB1);
    rs_scatter<true, false><<<BN * NB1, 256, 0, stream>>>(nullptr, logits, kv1B, nullptr, hist, N1, NB1, 0);
  }
  u64* src = kv1B; u64* dst = kv1A;
  for (int p = 1; p < 4; ++p) {
    u32* gT = gTotAll + (size_t)p * BN * 256;
    rs_hist<false><<<BN * NB1, 256, 0, stream>>>(src, nullptr, hist, gT, N1, NB1, p * 8);
    rs_scanB<<<BN * 64, 256, 0, stream>>>(hist, gT, NB1);
    if (p < 3) {
      rs_scatter<false, false><<<BN * NB1, 256, 0, stream>>>(src, nullptr, dst, nullptr, hist, N1, NB1, p * 8);
      u64* tmp = src; src = dst; dst = tmp;
    } else {
      rs_scatter<false, true><<<BN * NB1, 256, 0, stream>>>(src, nullptr, nullptr, addr, hist, N1, NB1, p * 8);
    }
  }

  // conv1 + permutation scatter into mem [B][N1][8]; k==0 blocks also build addr3
  conv1_scatter<<<BN * 3 * 64, 256, 0, stream>>>(addr, w1, b1, mem, addr3);

  // conv2 + adaptive pool (two-stage deterministic reduction)
  c2p1<<<BN * 256, 256, 0, stream>>>(mem, w2, b2, gPartial);
  c2p2<<<BN, 256, 0, stream>>>(gPartial, flatS);

  // projection GEMV (+ sort-2 key build)
  proj_k<<<NOPS_ / 16, 256, 0, stream>>>(flatS, pw, pb, kv2A);

  // sort 2: stable argsort of op_logits
  src = kv2A; dst = kv2B;
  for (int p = 0; p < 4; ++p) {
    u32* gT = gTotAll + (size_t)(4 + p) * BN * 256;
    rs_hist<false><<<BN * NB2, 256, 0, stream>>>(src, nullptr, hist, gT, NOPS_, NB2, p * 8);
    rs_scanB<<<BN * 64, 256, 0, stream>>>(hist, gT, NB2);
    if (p < 3) {
      rs_scatter<false, false><<<BN * NB2, 256, 0, stream>>>(src, nullptr, dst, nullptr, hist, NOPS_, NB2, p * 8);
      u64* tmp = src; src = dst; dst = tmp;
    } else {
      rs_scatter<false, true><<<BN * NB2, 256, 0, stream>>>(src, nullptr, nullptr, perm, hist, NOPS_, NB2, p * 8);
    }
  }

  // staged penalties + fused final reduce (last-block pattern)
  penalty_k<<<BN * 64, 256, 0, stream>>>(perm, addr3, partials, ctr, out);
}